// Round 5
// baseline (473.799 us; speedup 1.0000x reference)
//
#include <hip/hip_runtime.h>

#define TPB 256
#define NBLK1 256          // pass-1 blocks
#define BSH 10             // bucket shift: 1024 nodes per bucket
#define MAXBE 12288        // max edges/bucket (mean 10240, +20 sigma) -> 48KB LDS

static inline int cdiv(long long a, int b){ return (int)((a + b - 1)/b); }

// ---------- CSR build: two-level counting sort, no global atomics ----------

__global__ void k_bcount(const int* __restrict__ dst, int* __restrict__ cnt_t,
                         int E, int NB, int chunk){
    __shared__ int hist[256];
    int blk = blockIdx.x;
    for(int i = threadIdx.x; i < NB; i += blockDim.x) hist[i] = 0;
    __syncthreads();
    int lo = blk*chunk, hi = min(E, lo + chunk);
    for(int e = lo + threadIdx.x; e < hi; e += blockDim.x)
        atomicAdd(&hist[dst[e] >> BSH], 1);
    __syncthreads();
    for(int b = threadIdx.x; b < NB; b += blockDim.x)
        cnt_t[b*NBLK1 + blk] = hist[b];
}

__global__ void k_bscan(int* __restrict__ cnt_t, int M){
    __shared__ int part[1024];
    int t = threadIdx.x;
    int IT = (M + 1023) >> 10;
    int base = t*IT;
    int s = 0;
    for(int i = 0; i < IT; i++){ int k = base + i; if(k < M) s += cnt_t[k]; }
    part[t] = s;
    __syncthreads();
    for(int off = 1; off < 1024; off <<= 1){
        int u = (t >= off) ? part[t-off] : 0;
        __syncthreads();
        part[t] += u;
        __syncthreads();
    }
    int run = (t == 0) ? 0 : part[t-1];
    for(int i = 0; i < IT; i++){
        int k = base + i;
        if(k < M){ int v = cnt_t[k]; cnt_t[k] = run; run += v; }
    }
}

__global__ void k_bscatter(const int* __restrict__ ei, const int* __restrict__ cnt_t,
                           int2* __restrict__ pairs, int E, int NB, int chunk){
    __shared__ int cur[256];
    int blk = blockIdx.x;
    for(int b = threadIdx.x; b < NB; b += blockDim.x) cur[b] = cnt_t[b*NBLK1 + blk];
    __syncthreads();
    int lo = blk*chunk, hi = min(E, lo + chunk);
    for(int e = lo + threadIdx.x; e < hi; e += blockDim.x){
        int s = ei[e], d = ei[E + e];
        int pos = atomicAdd(&cur[d >> BSH], 1);    // LDS atomic
        pairs[pos] = make_int2(s, d);
    }
}

__global__ void k_build(const int2* __restrict__ pairs, const int* __restrict__ cnt_t,
                        int* __restrict__ csr, int* __restrict__ cursor,
                        float* __restrict__ dinv, int N, int E, int NB){
    __shared__ int c[1024];
    __shared__ int so[1024];
    __shared__ int part[256];
    __shared__ int csrl[MAXBE];
    int b    = blockIdx.x;
    int n0   = b << BSH;
    int nn   = min(1024, N - n0);
    int base = cnt_t[b*NBLK1];
    int end  = (b+1 < NB) ? cnt_t[(b+1)*NBLK1] : E;
    int cntE = end - base;
    int t = threadIdx.x;
    for(int i = t; i < 1024; i += 256) c[i] = 0;
    __syncthreads();
    for(int i = t; i < cntE; i += 256)
        atomicAdd(&c[pairs[base + i].y - n0], 1);   // LDS atomic
    __syncthreads();
    int i0 = t*4;
    int l0 = c[i0], l1 = c[i0+1], l2 = c[i0+2], l3 = c[i0+3];
    part[t] = l0 + l1 + l2 + l3;
    __syncthreads();
    for(int off = 1; off < 256; off <<= 1){
        int u = (t >= off) ? part[t-off] : 0;
        __syncthreads();
        part[t] += u;
        __syncthreads();
    }
    int run = (t == 0) ? 0 : part[t-1];
    so[i0] = run; so[i0+1] = run + l0; so[i0+2] = run + l0 + l1; so[i0+3] = run + l0 + l1 + l2;
    __syncthreads();
    for(int i = t; i < nn; i += 256){
        int cc = c[i];
        cursor[n0 + i] = base + so[i] + cc;        // inclusive end offset
        dinv[n0 + i]   = rsqrtf((float)(cc + 1));  // +1 = self-loop
    }
    for(int i = t; i < 1024; i += 256) c[i] = so[i];
    __syncthreads();
    for(int i = t; i < cntE; i += 256){
        int2 p = pairs[base + i];
        int pos = atomicAdd(&c[p.y - n0], 1);      // LDS atomic
        csrl[pos] = p.x;
    }
    __syncthreads();
    for(int i = t; i < cntE; i += 256) csr[base + i] = csrl[i];   // coalesced
}

// ---------- compute ----------

__global__ void k_gemm(const float* __restrict__ h, const float* __restrict__ W,
                       float* __restrict__ t, int n, int fin, int fout4,
                       const float* __restrict__ dinv, const float* __restrict__ bias){
    extern __shared__ float sW[];
    int fout = fout4*4;
    for(int i = threadIdx.x; i < fin*fout; i += blockDim.x) sW[i] = W[i];
    __syncthreads();
    unsigned idx = blockIdx.x*blockDim.x + threadIdx.x;
    unsigned total = (unsigned)n * (unsigned)fout4;
    if(idx >= total) return;
    unsigned row = idx / fout4;
    unsigned cg  = idx - row*fout4;
    const float* hr = h + (size_t)row*fin;
    const float4* sWv = (const float4*)sW;
    float4 acc = {0.f,0.f,0.f,0.f};
    for(int k = 0; k < fin; k++){
        float hv = hr[k];
        float4 w = sWv[(unsigned)k*fout4 + cg];
        acc.x += hv*w.x; acc.y += hv*w.y; acc.z += hv*w.z; acc.w += hv*w.w;
    }
    if(bias){
        const float4* bv = (const float4*)bias;
        float4 b = bv[cg];
        acc.x = fmaxf(acc.x + b.x, 0.f); acc.y = fmaxf(acc.y + b.y, 0.f);
        acc.z = fmaxf(acc.z + b.z, 0.f); acc.w = fmaxf(acc.w + b.w, 0.f);
    }
    if(dinv){
        float dd = dinv[row];
        acc.x *= dd; acc.y *= dd; acc.z *= dd; acc.w *= dd;
    }
    ((float4*)t)[idx] = acc;
}

__global__ void k_gather(const int* __restrict__ cursor, const int* __restrict__ csr_src,
                         const float* __restrict__ t, const float* __restrict__ dinv,
                         const float* __restrict__ bias, float* __restrict__ out,
                         int n, int f4, int prescale_out){
    unsigned idx = blockIdx.x*blockDim.x + threadIdx.x;
    unsigned total = (unsigned)n * (unsigned)f4;
    if(idx >= total) return;
    unsigned d  = idx / f4;
    unsigned cg = idx - d*f4;
    int start = (d == 0) ? 0 : cursor[d-1];
    int end   = cursor[d];
    const float4* tv = (const float4*)t;
    float4 acc = tv[(size_t)d*f4 + cg];          // self-loop contribution
    int j = start;
    if(j < end){
        int sCur = csr_src[j];
        while(true){
            j++;
            int sNext = (j < end) ? csr_src[j] : 0;
            float4 v = tv[(size_t)sCur*f4 + cg];
            acc.x += v.x; acc.y += v.y; acc.z += v.z; acc.w += v.w;
            if(j >= end) break;
            sCur = sNext;
        }
    }
    float dd = dinv[d];
    acc.x *= dd; acc.y *= dd; acc.z *= dd; acc.w *= dd;
    if(bias){
        const float4* bv = (const float4*)bias;
        float4 b = bv[cg];
        acc.x = fmaxf(acc.x + b.x, 0.f); acc.y = fmaxf(acc.y + b.y, 0.f);
        acc.z = fmaxf(acc.z + b.z, 0.f); acc.w = fmaxf(acc.w + b.w, 0.f);
    }
    if(prescale_out){
        acc.x *= dd; acc.y *= dd; acc.z *= dd; acc.w *= dd;
    }
    ((float4*)out)[idx] = acc;
}

// one block (64 threads) per graph; batch sorted, segments non-empty.
__global__ void k_pool_seg(const float* __restrict__ h, const int* __restrict__ batch,
                           float* __restrict__ pooled, int n, int f4){
    int g = blockIdx.x;
    int lo = 0, hi = n;
    while(lo < hi){ int mid = (lo + hi) >> 1; if(batch[mid] < g) lo = mid + 1; else hi = mid; }
    int start = lo;
    hi = n;
    while(lo < hi){ int mid = (lo + hi) >> 1; if(batch[mid] < g + 1) lo = mid + 1; else hi = mid; }
    int end = lo;

    int t  = threadIdx.x;
    int rg = t >> 4;
    int cg = t & 15;
    float4 m = {0.f, 0.f, 0.f, 0.f};
    if(cg < f4){
        for(int r = start + rg; r < end; r += 4){
            float4 v = ((const float4*)h)[(size_t)r*f4 + cg];
            m.x = fmaxf(m.x, v.x); m.y = fmaxf(m.y, v.y);
            m.z = fmaxf(m.z, v.z); m.w = fmaxf(m.w, v.w);
        }
    }
    for(int off = 32; off >= 16; off >>= 1){
        m.x = fmaxf(m.x, __shfl_xor(m.x, off, 64));
        m.y = fmaxf(m.y, __shfl_xor(m.y, off, 64));
        m.z = fmaxf(m.z, __shfl_xor(m.z, off, 64));
        m.w = fmaxf(m.w, __shfl_xor(m.w, off, 64));
    }
    if(t < f4) ((float4*)pooled)[(size_t)g*f4 + t] = m;
}

// Head as tiled GEMM: 4 graphs/block, blockDim 256 (4 waves = 4 K-quarters).
// Requires H == 128 (thread h-mapping), FEAT <= 1024 (LDS staging).
__global__ void k_head4(const float* __restrict__ feature, const float* __restrict__ Wf1,
                        const float* __restrict__ bf1, const float* __restrict__ Wf2,
                        const float* __restrict__ bf2, const float* __restrict__ pooled,
                        const float* __restrict__ Wg, const float* __restrict__ bg,
                        float* __restrict__ out, int FEAT, int H, int F){
    __shared__ float sfeat[4*1024];   // 4 feature rows
    __shared__ float spart[3*512];    // K-partials from waves 1..3: [kk-1][g][h]
    __shared__ float sred[8];         // x2[0..3], x1[4..7]
    int g0 = blockIdx.x*4;
    int t  = threadIdx.x;

    // stage 4 contiguous feature rows (rows are adjacent in memory)
    const float* fr = feature + (size_t)g0*FEAT;
    for(int i = t; i < 4*FEAT; i += 256) sfeat[i] = fr[i];
    __syncthreads();

    int kk = t >> 6;                  // K-quarter (one per wave)
    int h2 = t & 63;                  // float2 column: h = 2*h2, 2*h2+1
    int KQ = (FEAT + 3) >> 2;
    int k0 = kk*KQ, k1 = min(FEAT, k0 + KQ);
    float2 a0={0,0}, a1={0,0}, a2={0,0}, a3={0,0};   // 8 independent FMA chains
    for(int k = k0; k < k1; k++){
        float2 w = ((const float2*)(Wf1 + (size_t)k*H))[h2];
        float f0 = sfeat[k], f1 = sfeat[FEAT+k], f2 = sfeat[2*FEAT+k], f3 = sfeat[3*FEAT+k];
        a0.x += f0*w.x; a0.y += f0*w.y;
        a1.x += f1*w.x; a1.y += f1*w.y;
        a2.x += f2*w.x; a2.y += f2*w.y;
        a3.x += f3*w.x; a3.y += f3*w.y;
    }
    if(kk > 0){
        float2* p = (float2*)(spart + (kk-1)*512);
        p[h2] = a0; p[64+h2] = a1; p[128+h2] = a2; p[192+h2] = a3;
    }
    __syncthreads();
    if(kk == 0){
        // combine partials, bias+relu, *Wf2, reduce over h
        float2* p1 = (float2*)(spart);
        float2* p2 = (float2*)(spart + 512);
        float2* p3 = (float2*)(spart + 1024);
        float2 b  = ((const float2*)bf1)[h2];
        float2 w2 = ((const float2*)Wf2)[h2];
        float2 accs[4] = {a0, a1, a2, a3};
        for(int g = 0; g < 4; g++){
            float2 v  = accs[g];
            float2 q1 = p1[g*64+h2], q2 = p2[g*64+h2], q3 = p3[g*64+h2];
            float hx = fmaxf(v.x + q1.x + q2.x + q3.x + b.x, 0.f);
            float hy = fmaxf(v.y + q1.y + q2.y + q3.y + b.y, 0.f);
            float y = hx*w2.x + hy*w2.y;
            for(int off = 32; off; off >>= 1) y += __shfl_xor(y, off, 64);
            if(h2 == 0) sred[g] = y + bf2[0];
        }
    } else if(kk == 1){
        // x1 = relu(pooled . Wg + bg) for the 4 graphs
        int c = h2;
        float wgv = (c < F) ? Wg[c] : 0.f;
        for(int g = 0; g < 4; g++){
            float v = (c < F) ? pooled[(size_t)(g0+g)*F + c]*wgv : 0.f;
            for(int off = 32; off; off >>= 1) v += __shfl_xor(v, off, 64);
            if(h2 == 0) sred[4+g] = fmaxf(v + bg[0], 0.f);
        }
    }
    __syncthreads();
    if(t < 4) out[g0 + t] = sred[t] + sred[4 + t];
}

extern "C" void kernel_launch(void* const* d_in, const int* in_sizes, int n_in,
                              void* d_out, int out_size, void* d_ws, size_t ws_size,
                              hipStream_t stream) {
    const float* x       = (const float*)d_in[0];
    const int*   ei      = (const int*)  d_in[1];
    const int*   batch   = (const int*)  d_in[2];
    const float* feature = (const float*)d_in[3];
    const float* W1 = (const float*)d_in[4];  const float* b1 = (const float*)d_in[5];
    const float* W2 = (const float*)d_in[6];  const float* b2 = (const float*)d_in[7];
    const float* W3 = (const float*)d_in[8];  const float* b3 = (const float*)d_in[9];
    const float* Wg = (const float*)d_in[10]; const float* bg = (const float*)d_in[11];
    const float* Wf1= (const float*)d_in[12]; const float* bf1= (const float*)d_in[13];
    const float* Wf2= (const float*)d_in[14]; const float* bf2= (const float*)d_in[15];
    float* out = (float*)d_out;

    const int N    = in_sizes[2];          // 100000
    const int E    = in_sizes[1] / 2;      // 1000000
    const int G    = out_size;             // 1024
    const int F    = in_sizes[5];          // 44
    const int F2   = in_sizes[7];          // 88
    const int FEAT = in_sizes[3] / G;      // 1019
    const int H    = in_sizes[13];         // 128
    const int F4   = F  / 4;               // 11
    const int F24  = F2 / 4;               // 22

    const int NB    = cdiv(N, 1 << BSH);   // 98 coarse buckets
    const int chunk = cdiv(E, NBLK1);
    const int M     = NB * NBLK1;

    // workspace layout (4B units)
    float* wsf    = (float*)d_ws;
    float* dinv   = wsf;                        // N floats
    int*   cursor = (int*)(dinv + N);           // N ints
    int*   csr    = cursor + N;                 // E ints
    float* bufA   = (float*)(csr + E);          // N*F
    float* bufB   = bufA + (size_t)N*F;         // N*F2
    float* bufC   = bufB + (size_t)N*F2;        // N*F
    float* pooled = bufC + (size_t)N*F;         // G*F
    // pairs + cnt_t time-share bufB (dead until conv2's GEMM writes bufB)
    int2*  pairs  = (int2*)bufB;                // E int2
    int*   cnt_t  = (int*)bufB + 2*(size_t)E;   // M ints

    // ---- CSR build (counting sort; no global atomics) ----
    k_bcount  <<<NBLK1, TPB, 0, stream>>>(ei + E, cnt_t, E, NB, chunk);
    k_bscan   <<<1, 1024, 0, stream>>>(cnt_t, M);
    k_bscatter<<<NBLK1, TPB, 0, stream>>>(ei, cnt_t, pairs, E, NB, chunk);
    k_build   <<<NB, TPB, 0, stream>>>(pairs, cnt_t, csr, cursor, dinv, N, E, NB);

    // ---- conv1 (transform-first) ----
    {
        unsigned tot = (unsigned)N*F4;
        k_gemm<<<cdiv(tot,TPB), TPB, F*F*sizeof(float), stream>>>(x, W1, bufA, N, F, F4, dinv, nullptr);
        k_gather<<<cdiv(tot,TPB), TPB, 0, stream>>>(cursor, csr, bufA, dinv, b1, bufC, N, F4, 1);
    }
    // ---- conv2 (aggregate-first) ----
    {
        unsigned tot = (unsigned)N*F4;
        k_gather<<<cdiv(tot,TPB), TPB, 0, stream>>>(cursor, csr, bufC, dinv, nullptr, bufA, N, F4, 0);
        unsigned tot2 = (unsigned)N*F24;
        k_gemm<<<cdiv(tot2,TPB), TPB, F*F2*sizeof(float), stream>>>(bufA, W2, bufB, N, F, F24, nullptr, b2);
    }
    // ---- conv3 (transform-first) ----
    {
        unsigned tot = (unsigned)N*F4;
        k_gemm<<<cdiv(tot,TPB), TPB, F2*F*sizeof(float), stream>>>(bufB, W3, bufA, N, F2, F4, dinv, nullptr);
        k_gather<<<cdiv(tot,TPB), TPB, 0, stream>>>(cursor, csr, bufA, dinv, b3, bufC, N, F4, 0);
    }
    // ---- global max pool ----
    k_pool_seg<<<G, 64, 0, stream>>>(bufC, batch, pooled, N, F4);

    // ---- heads (4 graphs per block) ----
    k_head4<<<G/4, 256, 0, stream>>>(
        feature, Wf1, bf1, Wf2, bf2, pooled, Wg, bg, out, FEAT, H, F);
}

// Round 6
// 421.430 us; speedup vs baseline: 1.1243x; 1.1243x over previous
//
#include <hip/hip_runtime.h>

#define TPB 256
#define NBLK1 256          // pass-1 blocks
#define BSH 10             // bucket shift: 1024 nodes per bucket
#define MAXBE 12288        // max edges/bucket (mean 10240) -> 48KB LDS
#define KS 8               // head GEMM K-splits
#define GB 8               // head GEMM graphs per block

static inline int cdiv(long long a, int b){ return (int)((a + b - 1)/b); }

// ---------- CSR build: two-level counting sort, no global atomics ----------

__global__ void k_bcount(const int* __restrict__ dst, int* __restrict__ cnt_t,
                         int E, int NB, int chunk){
    __shared__ int hist[256];
    int blk = blockIdx.x;
    for(int i = threadIdx.x; i < NB; i += blockDim.x) hist[i] = 0;
    __syncthreads();
    int lo = blk*chunk, hi = min(E, lo + chunk);
    for(int e = lo + threadIdx.x; e < hi; e += blockDim.x)
        atomicAdd(&hist[dst[e] >> BSH], 1);
    __syncthreads();
    for(int b = threadIdx.x; b < NB; b += blockDim.x)
        cnt_t[b*NBLK1 + blk] = hist[b];
}

__global__ void k_bscan(int* __restrict__ cnt_t, int M){
    __shared__ int part[1024];
    int t = threadIdx.x;
    int IT = (M + 1023) >> 10;
    int base = t*IT;
    int s = 0;
    for(int i = 0; i < IT; i++){ int k = base + i; if(k < M) s += cnt_t[k]; }
    part[t] = s;
    __syncthreads();
    for(int off = 1; off < 1024; off <<= 1){
        int u = (t >= off) ? part[t-off] : 0;
        __syncthreads();
        part[t] += u;
        __syncthreads();
    }
    int run = (t == 0) ? 0 : part[t-1];
    for(int i = 0; i < IT; i++){
        int k = base + i;
        if(k < M){ int v = cnt_t[k]; cnt_t[k] = run; run += v; }
    }
}

__global__ void k_bscatter(const int* __restrict__ ei, const int* __restrict__ cnt_t,
                           int2* __restrict__ pairs, int E, int NB, int chunk){
    __shared__ int cur[256];
    int blk = blockIdx.x;
    for(int b = threadIdx.x; b < NB; b += blockDim.x) cur[b] = cnt_t[b*NBLK1 + blk];
    __syncthreads();
    int lo = blk*chunk, hi = min(E, lo + chunk);
    for(int e = lo + threadIdx.x; e < hi; e += blockDim.x){
        int s = ei[e], d = ei[E + e];
        int pos = atomicAdd(&cur[d >> BSH], 1);    // LDS atomic
        pairs[pos] = make_int2(s, d);
    }
}

__global__ void k_build(const int2* __restrict__ pairs, const int* __restrict__ cnt_t,
                        int* __restrict__ csr, int* __restrict__ cursor,
                        float* __restrict__ dinv, int N, int E, int NB){
    __shared__ int c[1024];
    __shared__ int so[1024];
    __shared__ int part[256];
    __shared__ int csrl[MAXBE];
    int b    = blockIdx.x;
    int n0   = b << BSH;
    int nn   = min(1024, N - n0);
    int base = cnt_t[b*NBLK1];
    int end  = (b+1 < NB) ? cnt_t[(b+1)*NBLK1] : E;
    int cntE = end - base;
    int t = threadIdx.x;
    for(int i = t; i < 1024; i += 256) c[i] = 0;
    __syncthreads();
    for(int i = t; i < cntE; i += 256)
        atomicAdd(&c[pairs[base + i].y - n0], 1);   // LDS atomic
    __syncthreads();
    int i0 = t*4;
    int l0 = c[i0], l1 = c[i0+1], l2 = c[i0+2], l3 = c[i0+3];
    part[t] = l0 + l1 + l2 + l3;
    __syncthreads();
    for(int off = 1; off < 256; off <<= 1){
        int u = (t >= off) ? part[t-off] : 0;
        __syncthreads();
        part[t] += u;
        __syncthreads();
    }
    int run = (t == 0) ? 0 : part[t-1];
    so[i0] = run; so[i0+1] = run + l0; so[i0+2] = run + l0 + l1; so[i0+3] = run + l0 + l1 + l2;
    __syncthreads();
    for(int i = t; i < nn; i += 256){
        int cc = c[i];
        cursor[n0 + i] = base + so[i] + cc;        // inclusive end offset
        dinv[n0 + i]   = rsqrtf((float)(cc + 1));  // +1 = self-loop
    }
    for(int i = t; i < 1024; i += 256) c[i] = so[i];
    __syncthreads();
    for(int i = t; i < cntE; i += 256){
        int2 p = pairs[base + i];
        int pos = atomicAdd(&c[p.y - n0], 1);      // LDS atomic
        csrl[pos] = p.x;
    }
    __syncthreads();
    for(int i = t; i < cntE; i += 256) csr[base + i] = csrl[i];   // coalesced
}

// ---------- compute ----------

__global__ void k_gemm(const float* __restrict__ h, const float* __restrict__ W,
                       float* __restrict__ t, int n, int fin, int fout4,
                       const float* __restrict__ dinv, const float* __restrict__ bias){
    extern __shared__ float sW[];
    int fout = fout4*4;
    for(int i = threadIdx.x; i < fin*fout; i += blockDim.x) sW[i] = W[i];
    __syncthreads();
    unsigned idx = blockIdx.x*blockDim.x + threadIdx.x;
    unsigned total = (unsigned)n * (unsigned)fout4;
    if(idx >= total) return;
    unsigned row = idx / fout4;
    unsigned cg  = idx - row*fout4;
    const float* hr = h + (size_t)row*fin;
    const float4* sWv = (const float4*)sW;
    float4 acc = {0.f,0.f,0.f,0.f};
    for(int k = 0; k < fin; k++){
        float hv = hr[k];
        float4 w = sWv[(unsigned)k*fout4 + cg];
        acc.x += hv*w.x; acc.y += hv*w.y; acc.z += hv*w.z; acc.w += hv*w.w;
    }
    if(bias){
        const float4* bv = (const float4*)bias;
        float4 b = bv[cg];
        acc.x = fmaxf(acc.x + b.x, 0.f); acc.y = fmaxf(acc.y + b.y, 0.f);
        acc.z = fmaxf(acc.z + b.z, 0.f); acc.w = fmaxf(acc.w + b.w, 0.f);
    }
    if(dinv){
        float dd = dinv[row];
        acc.x *= dd; acc.y *= dd; acc.z *= dd; acc.w *= dd;
    }
    ((float4*)t)[idx] = acc;
}

__global__ void k_gather(const int* __restrict__ cursor, const int* __restrict__ csr_src,
                         const float* __restrict__ t, const float* __restrict__ dinv,
                         const float* __restrict__ bias, float* __restrict__ out,
                         int n, int f4, int prescale_out){
    unsigned idx = blockIdx.x*blockDim.x + threadIdx.x;
    unsigned total = (unsigned)n * (unsigned)f4;
    if(idx >= total) return;
    unsigned d  = idx / f4;
    unsigned cg = idx - d*f4;
    int start = (d == 0) ? 0 : cursor[d-1];
    int end   = cursor[d];
    const float4* tv = (const float4*)t;
    float4 acc = tv[(size_t)d*f4 + cg];          // self-loop contribution
    int j = start;
    if(j < end){
        int sCur = csr_src[j];
        while(true){
            j++;
            int sNext = (j < end) ? csr_src[j] : 0;
            float4 v = tv[(size_t)sCur*f4 + cg];
            acc.x += v.x; acc.y += v.y; acc.z += v.z; acc.w += v.w;
            if(j >= end) break;
            sCur = sNext;
        }
    }
    float dd = dinv[d];
    acc.x *= dd; acc.y *= dd; acc.z *= dd; acc.w *= dd;
    if(bias){
        const float4* bv = (const float4*)bias;
        float4 b = bv[cg];
        acc.x = fmaxf(acc.x + b.x, 0.f); acc.y = fmaxf(acc.y + b.y, 0.f);
        acc.z = fmaxf(acc.z + b.z, 0.f); acc.w = fmaxf(acc.w + b.w, 0.f);
    }
    if(prescale_out){
        acc.x *= dd; acc.y *= dd; acc.z *= dd; acc.w *= dd;
    }
    ((float4*)out)[idx] = acc;
}

// one block (64 threads) per graph; batch sorted, segments non-empty.
__global__ void k_pool_seg(const float* __restrict__ h, const int* __restrict__ batch,
                           float* __restrict__ pooled, int n, int f4){
    int g = blockIdx.x;
    int lo = 0, hi = n;
    while(lo < hi){ int mid = (lo + hi) >> 1; if(batch[mid] < g) lo = mid + 1; else hi = mid; }
    int start = lo;
    hi = n;
    while(lo < hi){ int mid = (lo + hi) >> 1; if(batch[mid] < g + 1) lo = mid + 1; else hi = mid; }
    int end = lo;

    int t  = threadIdx.x;
    int rg = t >> 4;
    int cg = t & 15;
    float4 m = {0.f, 0.f, 0.f, 0.f};
    if(cg < f4){
        for(int r = start + rg; r < end; r += 4){
            float4 v = ((const float4*)h)[(size_t)r*f4 + cg];
            m.x = fmaxf(m.x, v.x); m.y = fmaxf(m.y, v.y);
            m.z = fmaxf(m.z, v.z); m.w = fmaxf(m.w, v.w);
        }
    }
    for(int off = 32; off >= 16; off >>= 1){
        m.x = fmaxf(m.x, __shfl_xor(m.x, off, 64));
        m.y = fmaxf(m.y, __shfl_xor(m.y, off, 64));
        m.z = fmaxf(m.z, __shfl_xor(m.z, off, 64));
        m.w = fmaxf(m.w, __shfl_xor(m.w, off, 64));
    }
    if(t < f4) ((float4*)pooled)[(size_t)g*f4 + t] = m;
}

// ---------- head: split-K GEMM ----------
// grid (G/GB, KS), 256 threads. partial[ks][g][h] = feature[g, k0:k1] @ Wf1[k0:k1, h]
// thread: h = t&127, owns 4 graphs (gq = t>>7; g = gq*4+i). Requires H==128.
__global__ void k_headmm(const float* __restrict__ feature, const float* __restrict__ Wf1,
                         float* __restrict__ partial, int G, int FEAT, int H){
    __shared__ float sfeat[128*GB];     // [k][g] transposed tile, 4 KB
    int g0 = blockIdx.x*GB;
    int ks = blockIdx.y;
    int Kc = (FEAT + KS - 1)/KS;        // 128
    int k0 = ks*Kc;
    int k1 = min(FEAT, k0 + Kc);
    int kc = k1 - k0;
    int t  = threadIdx.x;

    // stage feature tile transposed: sfeat[kk*GB + gi]
    for(int idx = t; idx < GB*128; idx += 256){
        int gi = idx >> 7, kk = idx & 127;
        if(kk < kc) sfeat[kk*GB + gi] = feature[(size_t)(g0+gi)*FEAT + k0 + kk];
    }
    __syncthreads();

    int h  = t & 127;
    int gq = t >> 7;                    // 0/1 -> graphs gq*4 .. gq*4+3
    const float* wp = Wf1 + (size_t)k0*H + h;
    float4 a = {0.f,0.f,0.f,0.f};
    const float4* sf = (const float4*)(sfeat) + gq;   // sfeat[kk*8 + gq*4] as float4
    for(int kk = 0; kk < kc; kk++){
        float w = wp[(size_t)kk*H];                   // coalesced, independent stream
        float4 f = sf[kk*2];                          // broadcast b128
        a.x += f.x*w; a.y += f.y*w; a.z += f.z*w; a.w += f.w*w;
    }
    float* pp = partial + ((size_t)ks*G + g0 + gq*4)*H + h;
    pp[0] = a.x; pp[H] = a.y; pp[2*H] = a.z; pp[3*H] = a.w;
}

// combine partials + epilogue. 4 graphs/block (one per wave), 256 threads.
// x2 = relu(C + bf1) @ Wf2 + bf2 ; x1 = relu(pooled.Wg + bg); out = x1 + x2.
// Requires H==128 (h2 = lane covers 2 h), F <= 64.
__global__ void k_headfin(const float* __restrict__ partial, const float* __restrict__ bf1,
                          const float* __restrict__ Wf2, const float* __restrict__ bf2,
                          const float* __restrict__ pooled, const float* __restrict__ Wg,
                          const float* __restrict__ bg, float* __restrict__ out,
                          int G, int H, int F){
    int g  = blockIdx.x*4 + (threadIdx.x >> 6);
    int h2 = threadIdx.x & 63;
    float2 s = {0.f, 0.f};
    for(int ks = 0; ks < KS; ks++){
        float2 p = ((const float2*)(partial + ((size_t)ks*G + g)*H))[h2];
        s.x += p.x; s.y += p.y;
    }
    float2 b  = ((const float2*)bf1)[h2];
    float2 w2 = ((const float2*)Wf2)[h2];
    float y = fmaxf(s.x + b.x, 0.f)*w2.x + fmaxf(s.y + b.y, 0.f)*w2.y;
    float v = (h2 < F) ? pooled[(size_t)g*F + h2]*Wg[h2] : 0.f;
    for(int off = 32; off; off >>= 1){
        y += __shfl_xor(y, off, 64);
        v += __shfl_xor(v, off, 64);
    }
    if(h2 == 0) out[g] = fmaxf(v + bg[0], 0.f) + y + bf2[0];
}

extern "C" void kernel_launch(void* const* d_in, const int* in_sizes, int n_in,
                              void* d_out, int out_size, void* d_ws, size_t ws_size,
                              hipStream_t stream) {
    const float* x       = (const float*)d_in[0];
    const int*   ei      = (const int*)  d_in[1];
    const int*   batch   = (const int*)  d_in[2];
    const float* feature = (const float*)d_in[3];
    const float* W1 = (const float*)d_in[4];  const float* b1 = (const float*)d_in[5];
    const float* W2 = (const float*)d_in[6];  const float* b2 = (const float*)d_in[7];
    const float* W3 = (const float*)d_in[8];  const float* b3 = (const float*)d_in[9];
    const float* Wg = (const float*)d_in[10]; const float* bg = (const float*)d_in[11];
    const float* Wf1= (const float*)d_in[12]; const float* bf1= (const float*)d_in[13];
    const float* Wf2= (const float*)d_in[14]; const float* bf2= (const float*)d_in[15];
    float* out = (float*)d_out;

    const int N    = in_sizes[2];          // 100000
    const int E    = in_sizes[1] / 2;      // 1000000
    const int G    = out_size;             // 1024
    const int F    = in_sizes[5];          // 44
    const int F2   = in_sizes[7];          // 88
    const int FEAT = in_sizes[3] / G;      // 1019
    const int H    = in_sizes[13];         // 128
    const int F4   = F  / 4;               // 11
    const int F24  = F2 / 4;               // 22

    const int NB    = cdiv(N, 1 << BSH);   // 98 coarse buckets
    const int chunk = cdiv(E, NBLK1);
    const int M     = NB * NBLK1;

    // workspace layout (4B units)
    float* wsf    = (float*)d_ws;
    float* dinv   = wsf;                        // N floats
    int*   cursor = (int*)(dinv + N);           // N ints
    int*   csr    = cursor + N;                 // E ints
    float* bufA   = (float*)(csr + E);          // N*F
    float* bufB   = bufA + (size_t)N*F;         // N*F2
    float* bufC   = bufB + (size_t)N*F2;        // N*F
    float* pooled = bufC + (size_t)N*F;         // G*F
    // time-shared aliases of bufB (dead outside conv2-out..conv3-in window):
    int2*  pairs  = (int2*)bufB;                // E int2   (CSR build)
    int*   cnt_t  = (int*)bufB + 2*(size_t)E;   // M ints   (CSR build)
    float* partial= bufB;                       // KS*G*H floats (head, after conv3 gemm)

    // ---- CSR build (counting sort; no global atomics) ----
    k_bcount  <<<NBLK1, TPB, 0, stream>>>(ei + E, cnt_t, E, NB, chunk);
    k_bscan   <<<1, 1024, 0, stream>>>(cnt_t, M);
    k_bscatter<<<NBLK1, TPB, 0, stream>>>(ei, cnt_t, pairs, E, NB, chunk);
    k_build   <<<NB, TPB, 0, stream>>>(pairs, cnt_t, csr, cursor, dinv, N, E, NB);

    // ---- conv1 (transform-first) ----
    {
        unsigned tot = (unsigned)N*F4;
        k_gemm<<<cdiv(tot,TPB), TPB, F*F*sizeof(float), stream>>>(x, W1, bufA, N, F, F4, dinv, nullptr);
        k_gather<<<cdiv(tot,TPB), TPB, 0, stream>>>(cursor, csr, bufA, dinv, b1, bufC, N, F4, 1);
    }
    // ---- conv2 (aggregate-first) ----
    {
        unsigned tot = (unsigned)N*F4;
        k_gather<<<cdiv(tot,TPB), TPB, 0, stream>>>(cursor, csr, bufC, dinv, nullptr, bufA, N, F4, 0);
        unsigned tot2 = (unsigned)N*F24;
        k_gemm<<<cdiv(tot2,TPB), TPB, F*F2*sizeof(float), stream>>>(bufA, W2, bufB, N, F, F24, nullptr, b2);
    }
    // ---- conv3 (transform-first) ----
    {
        unsigned tot = (unsigned)N*F4;
        k_gemm<<<cdiv(tot,TPB), TPB, F2*F*sizeof(float), stream>>>(bufB, W3, bufA, N, F2, F4, dinv, nullptr);
        k_gather<<<cdiv(tot,TPB), TPB, 0, stream>>>(cursor, csr, bufA, dinv, b3, bufC, N, F4, 0);
    }
    // ---- global max pool ----
    k_pool_seg<<<G, 64, 0, stream>>>(bufC, batch, pooled, N, F4);

    // ---- head: split-K GEMM into partial (aliases bufB; conv3 gemm already consumed it) ----
    {
        dim3 grid(G/GB, KS);
        k_headmm<<<grid, 256, 0, stream>>>(feature, Wf1, partial, G, FEAT, H);
        k_headfin<<<G/4, 256, 0, stream>>>(partial, bf1, Wf2, bf2, pooled, Wg, bg, out, G, H, F);
    }
}

// Round 7
// 385.595 us; speedup vs baseline: 1.2287x; 1.0929x over previous
//
#include <hip/hip_runtime.h>
#include <hip/hip_fp16.h>

#define TPB 256
#define NBLK1 256          // pass-1 blocks
#define BSH 10             // bucket shift: 1024 nodes per bucket
#define MAXBE 12288        // max edges/bucket (mean 10240) -> 48KB LDS
#define KS 8               // head GEMM K-splits
#define GB 8               // head GEMM graphs per block

static inline int cdiv(long long a, int b){ return (int)((a + b - 1)/b); }

// 4 halves = 8 bytes
struct h4 { __half2 a, b; };
__device__ inline float4 h4tof4(h4 v){
    float2 lo = __half22float2(v.a), hi = __half22float2(v.b);
    return make_float4(lo.x, lo.y, hi.x, hi.y);
}
__device__ inline h4 f4toh4(float4 v){
    h4 r; r.a = __floats2half2_rn(v.x, v.y); r.b = __floats2half2_rn(v.z, v.w); return r;
}

// ---------- CSR build: two-level counting sort, no global atomics ----------

__global__ void k_bcount(const int* __restrict__ dst, int* __restrict__ cnt_t,
                         int E, int NB, int chunk){
    __shared__ int hist[256];
    int blk = blockIdx.x;
    for(int i = threadIdx.x; i < NB; i += blockDim.x) hist[i] = 0;
    __syncthreads();
    int lo = blk*chunk, hi = min(E, lo + chunk);
    for(int e = lo + threadIdx.x; e < hi; e += blockDim.x)
        atomicAdd(&hist[dst[e] >> BSH], 1);
    __syncthreads();
    for(int b = threadIdx.x; b < NB; b += blockDim.x)
        cnt_t[b*NBLK1 + blk] = hist[b];
}

__global__ void k_bscan(int* __restrict__ cnt_t, int M){
    __shared__ int part[1024];
    int t = threadIdx.x;
    int IT = (M + 1023) >> 10;
    int base = t*IT;
    int s = 0;
    for(int i = 0; i < IT; i++){ int k = base + i; if(k < M) s += cnt_t[k]; }
    part[t] = s;
    __syncthreads();
    for(int off = 1; off < 1024; off <<= 1){
        int u = (t >= off) ? part[t-off] : 0;
        __syncthreads();
        part[t] += u;
        __syncthreads();
    }
    int run = (t == 0) ? 0 : part[t-1];
    for(int i = 0; i < IT; i++){
        int k = base + i;
        if(k < M){ int v = cnt_t[k]; cnt_t[k] = run; run += v; }
    }
}

__global__ void k_bscatter(const int* __restrict__ ei, const int* __restrict__ cnt_t,
                           int2* __restrict__ pairs, int E, int NB, int chunk){
    __shared__ int cur[256];
    int blk = blockIdx.x;
    for(int b = threadIdx.x; b < NB; b += blockDim.x) cur[b] = cnt_t[b*NBLK1 + blk];
    __syncthreads();
    int lo = blk*chunk, hi = min(E, lo + chunk);
    for(int e = lo + threadIdx.x; e < hi; e += blockDim.x){
        int s = ei[e], d = ei[E + e];
        int pos = atomicAdd(&cur[d >> BSH], 1);    // LDS atomic
        pairs[pos] = make_int2(s, d);
    }
}

__global__ void k_build(const int2* __restrict__ pairs, const int* __restrict__ cnt_t,
                        int* __restrict__ csr, int* __restrict__ cursor,
                        float* __restrict__ dinv, int N, int E, int NB){
    __shared__ int c[1024];
    __shared__ int so[1024];
    __shared__ int part[256];
    __shared__ int csrl[MAXBE];
    int b    = blockIdx.x;
    int n0   = b << BSH;
    int nn   = min(1024, N - n0);
    int base = cnt_t[b*NBLK1];
    int end  = (b+1 < NB) ? cnt_t[(b+1)*NBLK1] : E;
    int cntE = end - base;
    int t = threadIdx.x;
    for(int i = t; i < 1024; i += 256) c[i] = 0;
    __syncthreads();
    for(int i = t; i < cntE; i += 256)
        atomicAdd(&c[pairs[base + i].y - n0], 1);   // LDS atomic
    __syncthreads();
    int i0 = t*4;
    int l0 = c[i0], l1 = c[i0+1], l2 = c[i0+2], l3 = c[i0+3];
    part[t] = l0 + l1 + l2 + l3;
    __syncthreads();
    for(int off = 1; off < 256; off <<= 1){
        int u = (t >= off) ? part[t-off] : 0;
        __syncthreads();
        part[t] += u;
        __syncthreads();
    }
    int run = (t == 0) ? 0 : part[t-1];
    so[i0] = run; so[i0+1] = run + l0; so[i0+2] = run + l0 + l1; so[i0+3] = run + l0 + l1 + l2;
    __syncthreads();
    for(int i = t; i < nn; i += 256){
        int cc = c[i];
        cursor[n0 + i] = base + so[i] + cc;        // inclusive end offset
        dinv[n0 + i]   = rsqrtf((float)(cc + 1));  // +1 = self-loop
    }
    for(int i = t; i < 1024; i += 256) c[i] = so[i];
    __syncthreads();
    for(int i = t; i < cntE; i += 256){
        int2 p = pairs[base + i];
        int pos = atomicAdd(&c[p.y - n0], 1);      // LDS atomic
        csrl[pos] = p.x;
    }
    __syncthreads();
    for(int i = t; i < cntE; i += 256) csr[base + i] = csrl[i];   // coalesced
}

// ---------- compute (fp16 at rest, fp32 accumulate) ----------

// t = h @ W -> h4 chunks; input TI = float or __half. fin_s = input row stride (elems),
// out_sc = output row stride in h4 chunks. optional dinv row-prescale, bias+relu.
template<typename TI>
__global__ void k_gemm(const TI* __restrict__ h, const float* __restrict__ W,
                       h4* __restrict__ t, int n, int fin, int fin_s, int fout4, int out_sc,
                       const float* __restrict__ dinv, const float* __restrict__ bias){
    extern __shared__ float sW[];
    int fout = fout4*4;
    for(int i = threadIdx.x; i < fin*fout; i += blockDim.x) sW[i] = W[i];
    __syncthreads();
    unsigned idx = blockIdx.x*blockDim.x + threadIdx.x;
    unsigned total = (unsigned)n * (unsigned)fout4;
    if(idx >= total) return;
    unsigned row = idx / fout4;
    unsigned cg  = idx - row*fout4;
    const TI* hr = h + (size_t)row*fin_s;
    const float4* sWv = (const float4*)sW;
    float4 acc = {0.f,0.f,0.f,0.f};
    for(int k = 0; k < fin; k++){
        float hv = (float)hr[k];
        float4 w = sWv[(unsigned)k*fout4 + cg];
        acc.x += hv*w.x; acc.y += hv*w.y; acc.z += hv*w.z; acc.w += hv*w.w;
    }
    if(bias){
        const float4* bv = (const float4*)bias;
        float4 b = bv[cg];
        acc.x = fmaxf(acc.x + b.x, 0.f); acc.y = fmaxf(acc.y + b.y, 0.f);
        acc.z = fmaxf(acc.z + b.z, 0.f); acc.w = fmaxf(acc.w + b.w, 0.f);
    }
    if(dinv){
        float dd = dinv[row];
        acc.x *= dd; acc.y *= dd; acc.z *= dd; acc.w *= dd;
    }
    t[(size_t)row*out_sc + cg] = f4toh4(acc);
}

// out[d] = f( dinv[d] * (t[d] + sum_{s->d} t[s]) ); rows are h4 chunks with stride sc
__global__ void k_gather(const int* __restrict__ cursor, const int* __restrict__ csr_src,
                         const h4* __restrict__ t, const float* __restrict__ dinv,
                         const float* __restrict__ bias, h4* __restrict__ out,
                         int n, int f4, int sc, int prescale_out){
    unsigned idx = blockIdx.x*blockDim.x + threadIdx.x;
    unsigned total = (unsigned)n * (unsigned)f4;
    if(idx >= total) return;
    unsigned d  = idx / f4;
    unsigned cg = idx - d*f4;
    int start = (d == 0) ? 0 : cursor[d-1];
    int end   = cursor[d];
    float4 acc = h4tof4(t[(size_t)d*sc + cg]);   // self-loop contribution
    int j = start;
    if(j < end){
        int sCur = csr_src[j];
        while(true){
            j++;
            int sNext = (j < end) ? csr_src[j] : 0;
            float4 v = h4tof4(t[(size_t)sCur*sc + cg]);
            acc.x += v.x; acc.y += v.y; acc.z += v.z; acc.w += v.w;
            if(j >= end) break;
            sCur = sNext;
        }
    }
    float dd = dinv[d];
    acc.x *= dd; acc.y *= dd; acc.z *= dd; acc.w *= dd;
    if(bias){
        const float4* bv = (const float4*)bias;
        float4 b = bv[cg];
        acc.x = fmaxf(acc.x + b.x, 0.f); acc.y = fmaxf(acc.y + b.y, 0.f);
        acc.z = fmaxf(acc.z + b.z, 0.f); acc.w = fmaxf(acc.w + b.w, 0.f);
    }
    if(prescale_out){
        acc.x *= dd; acc.y *= dd; acc.z *= dd; acc.w *= dd;
    }
    out[(size_t)d*sc + cg] = f4toh4(acc);
}

// one block (64 threads) per graph; batch sorted, segments non-empty. pooled fp32.
__global__ void k_pool_seg(const h4* __restrict__ h, const int* __restrict__ batch,
                           float* __restrict__ pooled, int n, int f4, int sc){
    int g = blockIdx.x;
    int lo = 0, hi = n;
    while(lo < hi){ int mid = (lo + hi) >> 1; if(batch[mid] < g) lo = mid + 1; else hi = mid; }
    int start = lo;
    hi = n;
    while(lo < hi){ int mid = (lo + hi) >> 1; if(batch[mid] < g + 1) lo = mid + 1; else hi = mid; }
    int end = lo;

    int t  = threadIdx.x;
    int rg = t >> 4;
    int cg = t & 15;
    float4 m = {0.f, 0.f, 0.f, 0.f};
    if(cg < f4){
        for(int r = start + rg; r < end; r += 4){
            float4 v = h4tof4(h[(size_t)r*sc + cg]);
            m.x = fmaxf(m.x, v.x); m.y = fmaxf(m.y, v.y);
            m.z = fmaxf(m.z, v.z); m.w = fmaxf(m.w, v.w);
        }
    }
    for(int off = 32; off >= 16; off >>= 1){
        m.x = fmaxf(m.x, __shfl_xor(m.x, off, 64));
        m.y = fmaxf(m.y, __shfl_xor(m.y, off, 64));
        m.z = fmaxf(m.z, __shfl_xor(m.z, off, 64));
        m.w = fmaxf(m.w, __shfl_xor(m.w, off, 64));
    }
    if(t < f4) ((float4*)pooled)[(size_t)g*f4 + t] = m;
}

// ---------- head: split-K GEMM ----------
__global__ void k_headmm(const float* __restrict__ feature, const float* __restrict__ Wf1,
                         float* __restrict__ partial, int G, int FEAT, int H){
    __shared__ float sfeat[128*GB];
    int g0 = blockIdx.x*GB;
    int ks = blockIdx.y;
    int Kc = (FEAT + KS - 1)/KS;
    int k0 = ks*Kc;
    int k1 = min(FEAT, k0 + Kc);
    int kc = k1 - k0;
    int t  = threadIdx.x;

    for(int idx = t; idx < GB*128; idx += 256){
        int gi = idx >> 7, kk = idx & 127;
        if(kk < kc) sfeat[kk*GB + gi] = feature[(size_t)(g0+gi)*FEAT + k0 + kk];
    }
    __syncthreads();

    int h  = t & 127;
    int gq = t >> 7;
    const float* wp = Wf1 + (size_t)k0*H + h;
    float4 a = {0.f,0.f,0.f,0.f};
    const float4* sf = (const float4*)(sfeat) + gq;
    for(int kk = 0; kk < kc; kk++){
        float w = wp[(size_t)kk*H];
        float4 f = sf[kk*2];
        a.x += f.x*w; a.y += f.y*w; a.z += f.z*w; a.w += f.w*w;
    }
    float* pp = partial + ((size_t)ks*G + g0 + gq*4)*H + h;
    pp[0] = a.x; pp[H] = a.y; pp[2*H] = a.z; pp[3*H] = a.w;
}

__global__ void k_headfin(const float* __restrict__ partial, const float* __restrict__ bf1,
                          const float* __restrict__ Wf2, const float* __restrict__ bf2,
                          const float* __restrict__ pooled, const float* __restrict__ Wg,
                          const float* __restrict__ bg, float* __restrict__ out,
                          int G, int H, int F){
    int g  = blockIdx.x*4 + (threadIdx.x >> 6);
    int h2 = threadIdx.x & 63;
    float2 s = {0.f, 0.f};
    for(int ks = 0; ks < KS; ks++){
        float2 p = ((const float2*)(partial + ((size_t)ks*G + g)*H))[h2];
        s.x += p.x; s.y += p.y;
    }
    float2 b  = ((const float2*)bf1)[h2];
    float2 w2 = ((const float2*)Wf2)[h2];
    float y = fmaxf(s.x + b.x, 0.f)*w2.x + fmaxf(s.y + b.y, 0.f)*w2.y;
    float v = (h2 < F) ? pooled[(size_t)g*F + h2]*Wg[h2] : 0.f;
    for(int off = 32; off; off >>= 1){
        y += __shfl_xor(y, off, 64);
        v += __shfl_xor(v, off, 64);
    }
    if(h2 == 0) out[g] = fmaxf(v + bg[0], 0.f) + y + bf2[0];
}

extern "C" void kernel_launch(void* const* d_in, const int* in_sizes, int n_in,
                              void* d_out, int out_size, void* d_ws, size_t ws_size,
                              hipStream_t stream) {
    const float* x       = (const float*)d_in[0];
    const int*   ei      = (const int*)  d_in[1];
    const int*   batch   = (const int*)  d_in[2];
    const float* feature = (const float*)d_in[3];
    const float* W1 = (const float*)d_in[4];  const float* b1 = (const float*)d_in[5];
    const float* W2 = (const float*)d_in[6];  const float* b2 = (const float*)d_in[7];
    const float* W3 = (const float*)d_in[8];  const float* b3 = (const float*)d_in[9];
    const float* Wg = (const float*)d_in[10]; const float* bg = (const float*)d_in[11];
    const float* Wf1= (const float*)d_in[12]; const float* bf1= (const float*)d_in[13];
    const float* Wf2= (const float*)d_in[14]; const float* bf2= (const float*)d_in[15];
    float* out = (float*)d_out;

    const int N    = in_sizes[2];          // 100000
    const int E    = in_sizes[1] / 2;      // 1000000
    const int G    = out_size;             // 1024
    const int F    = in_sizes[5];          // 44
    const int F2   = in_sizes[7];          // 88
    const int FEAT = in_sizes[3] / G;      // 1019
    const int H    = in_sizes[13];         // 128
    const int F4   = F  / 4;               // 11 chunks
    const int F24  = F2 / 4;               // 22 chunks
    const int SC   = 12;                   // F-row stride in h4 chunks (44 -> 48 halves, 96 B)
    const int SC2  = 22;                   // F2-row stride in h4 chunks (88 halves, packed)

    const int NB    = cdiv(N, 1 << BSH);   // 98 coarse buckets
    const int chunk = cdiv(E, NBLK1);
    const int M     = NB * NBLK1;

    // workspace layout (4B units)
    float* wsf    = (float*)d_ws;
    float* dinv   = wsf;                         // N floats
    int*   cursor = (int*)(dinv + N);            // N ints
    int*   csr    = cursor + N;                  // E ints
    h4*    bufA   = (h4*)(csr + E);              // N*SC h4  (= N*24 floats)
    h4*    bufB   = bufA + (size_t)N*SC;         // N*SC2 h4 (= N*44 floats)
    h4*    bufC   = bufB + (size_t)N*SC2;        // N*SC h4
    float* pooled = (float*)(bufC + (size_t)N*SC);  // G*F floats
    // time-shared aliases of bufB (dead outside conv2-out..conv3-in window):
    int2*  pairs  = (int2*)bufB;                 // E int2   (CSR build)
    int*   cnt_t  = (int*)bufB + 2*(size_t)E;    // M ints   (CSR build)
    float* partial= (float*)bufB;                // KS*G*H floats (head, after conv3 gemm)

    // ---- CSR build (counting sort; no global atomics) ----
    k_bcount  <<<NBLK1, TPB, 0, stream>>>(ei + E, cnt_t, E, NB, chunk);
    k_bscan   <<<1, 1024, 0, stream>>>(cnt_t, M);
    k_bscatter<<<NBLK1, TPB, 0, stream>>>(ei, cnt_t, pairs, E, NB, chunk);
    k_build   <<<NB, TPB, 0, stream>>>(pairs, cnt_t, csr, cursor, dinv, N, E, NB);

    // ---- conv1 (transform-first): bufA = dinv.*(x@W1) ; bufC = dinv.*relu(dinv*agg+b1) ----
    {
        unsigned tot = (unsigned)N*F4;
        k_gemm<float><<<cdiv(tot,TPB), TPB, F*F*sizeof(float), stream>>>(
            x, W1, bufA, N, F, F, F4, SC, dinv, nullptr);
        k_gather<<<cdiv(tot,TPB), TPB, 0, stream>>>(cursor, csr, bufA, dinv, b1, bufC, N, F4, SC, 1);
    }
    // ---- conv2 (aggregate-first): bufA = dinv*agg(bufC) ; bufB = relu(bufA@W2+b2) ----
    {
        unsigned tot = (unsigned)N*F4;
        k_gather<<<cdiv(tot,TPB), TPB, 0, stream>>>(cursor, csr, bufC, dinv, nullptr, bufA, N, F4, SC, 0);
        unsigned tot2 = (unsigned)N*F24;
        k_gemm<__half><<<cdiv(tot2,TPB), TPB, F*F2*sizeof(float), stream>>>(
            (const __half*)bufA, W2, bufB, N, F, SC*4, F24, SC2, nullptr, b2);
    }
    // ---- conv3 (transform-first): bufA = dinv.*(bufB@W3) ; bufC = relu(dinv*agg+b3) ----
    {
        unsigned tot = (unsigned)N*F4;
        k_gemm<__half><<<cdiv(tot,TPB), TPB, F2*F*sizeof(float), stream>>>(
            (const __half*)bufB, W3, bufA, N, F2, SC2*4, F4, SC, dinv, nullptr);
        k_gather<<<cdiv(tot,TPB), TPB, 0, stream>>>(cursor, csr, bufA, dinv, b3, bufC, N, F4, SC, 0);
    }
    // ---- global max pool ----
    k_pool_seg<<<G, 64, 0, stream>>>(bufC, batch, pooled, N, F4, SC);

    // ---- head: split-K GEMM into partial (aliases bufB; conv3 gemm already consumed it) ----
    {
        dim3 grid(G/GB, KS);
        k_headmm<<<grid, 256, 0, stream>>>(feature, Wf1, partial, G, FEAT, H);
        k_headfin<<<G/4, 256, 0, stream>>>(partial, bf1, Wf2, bf2, pooled, Wg, bg, out, G, H, F);
    }
}

// Round 8
// 359.466 us; speedup vs baseline: 1.3181x; 1.0727x over previous
//
#include <hip/hip_runtime.h>
#include <hip/hip_fp16.h>

#define TPB 256
#define NBLK1 256          // pass-1 blocks
#define BSH 10             // bucket shift: 1024 nodes per bucket
#define MAXBE 12288        // max edges/bucket (mean 10240) -> 48KB LDS
#define KS 8               // head GEMM K-splits
#define GB 8               // head GEMM graphs per block

static inline int cdiv(long long a, int b){ return (int)((a + b - 1)/b); }

// 4 halves = 8 bytes, 8-byte aligned so loads are single dwordx2
struct __align__(8) h4 { __half2 a, b; };
__device__ inline float4 h4tof4(h4 v){
    float2 lo = __half22float2(v.a), hi = __half22float2(v.b);
    return make_float4(lo.x, lo.y, hi.x, hi.y);
}
__device__ inline h4 f4toh4(float4 v){
    h4 r; r.a = __floats2half2_rn(v.x, v.y); r.b = __floats2half2_rn(v.z, v.w); return r;
}

// ---------- CSR build: two-level counting sort, no global atomics ----------

__global__ void k_bcount(const int* __restrict__ dst, int* __restrict__ cnt_t,
                         int E, int NB, int chunk){
    __shared__ int hist[256];
    int blk = blockIdx.x;
    for(int i = threadIdx.x; i < NB; i += blockDim.x) hist[i] = 0;
    __syncthreads();
    int lo = blk*chunk, hi = min(E, lo + chunk);
    for(int e = lo + threadIdx.x; e < hi; e += blockDim.x)
        atomicAdd(&hist[dst[e] >> BSH], 1);
    __syncthreads();
    for(int b = threadIdx.x; b < NB; b += blockDim.x)
        cnt_t[b*NBLK1 + blk] = hist[b];
}

__global__ void k_bscan(int* __restrict__ cnt_t, int M){
    __shared__ int part[1024];
    int t = threadIdx.x;
    int IT = (M + 1023) >> 10;
    int base = t*IT;
    int s = 0;
    for(int i = 0; i < IT; i++){ int k = base + i; if(k < M) s += cnt_t[k]; }
    part[t] = s;
    __syncthreads();
    for(int off = 1; off < 1024; off <<= 1){
        int u = (t >= off) ? part[t-off] : 0;
        __syncthreads();
        part[t] += u;
        __syncthreads();
    }
    int run = (t == 0) ? 0 : part[t-1];
    for(int i = 0; i < IT; i++){
        int k = base + i;
        if(k < M){ int v = cnt_t[k]; cnt_t[k] = run; run += v; }
    }
}

__global__ void k_bscatter(const int* __restrict__ ei, const int* __restrict__ cnt_t,
                           int2* __restrict__ pairs, int E, int NB, int chunk){
    __shared__ int cur[256];
    int blk = blockIdx.x;
    for(int b = threadIdx.x; b < NB; b += blockDim.x) cur[b] = cnt_t[b*NBLK1 + blk];
    __syncthreads();
    int lo = blk*chunk, hi = min(E, lo + chunk);
    for(int e = lo + threadIdx.x; e < hi; e += blockDim.x){
        int s = ei[e], d = ei[E + e];
        int pos = atomicAdd(&cur[d >> BSH], 1);    // LDS atomic
        pairs[pos] = make_int2(s, d);
    }
}

__global__ void k_build(const int2* __restrict__ pairs, const int* __restrict__ cnt_t,
                        int* __restrict__ csr, int* __restrict__ cursor,
                        float* __restrict__ dinv, int N, int E, int NB){
    __shared__ int c[1024];
    __shared__ int so[1024];
    __shared__ int part[256];
    __shared__ int csrl[MAXBE];
    int b    = blockIdx.x;
    int n0   = b << BSH;
    int nn   = min(1024, N - n0);
    int base = cnt_t[b*NBLK1];
    int end  = (b+1 < NB) ? cnt_t[(b+1)*NBLK1] : E;
    int cntE = end - base;
    int t = threadIdx.x;
    for(int i = t; i < 1024; i += 256) c[i] = 0;
    __syncthreads();
    for(int i = t; i < cntE; i += 256)
        atomicAdd(&c[pairs[base + i].y - n0], 1);   // LDS atomic
    __syncthreads();
    int i0 = t*4;
    int l0 = c[i0], l1 = c[i0+1], l2 = c[i0+2], l3 = c[i0+3];
    part[t] = l0 + l1 + l2 + l3;
    __syncthreads();
    for(int off = 1; off < 256; off <<= 1){
        int u = (t >= off) ? part[t-off] : 0;
        __syncthreads();
        part[t] += u;
        __syncthreads();
    }
    int run = (t == 0) ? 0 : part[t-1];
    so[i0] = run; so[i0+1] = run + l0; so[i0+2] = run + l0 + l1; so[i0+3] = run + l0 + l1 + l2;
    __syncthreads();
    for(int i = t; i < nn; i += 256){
        int cc = c[i];
        cursor[n0 + i] = base + so[i] + cc;        // inclusive end offset
        dinv[n0 + i]   = rsqrtf((float)(cc + 1));  // +1 = self-loop
    }
    for(int i = t; i < 1024; i += 256) c[i] = so[i];
    __syncthreads();
    for(int i = t; i < cntE; i += 256){
        int2 p = pairs[base + i];
        int pos = atomicAdd(&c[p.y - n0], 1);      // LDS atomic
        csrl[pos] = p.x;
    }
    __syncthreads();
    for(int i = t; i < cntE; i += 256) csr[base + i] = csrl[i];   // coalesced
}

// ---------- compute (fp16 at rest, fp32 accumulate) ----------

#define GEMM_BODY(LOAD_HV)                                                     \
    extern __shared__ float sW[];                                              \
    int fout = fout4*4;                                                        \
    int fin = fin4*4;                                                          \
    for(int i = threadIdx.x; i < fin*fout; i += blockDim.x) sW[i] = W[i];      \
    __syncthreads();                                                           \
    unsigned idx = blockIdx.x*blockDim.x + threadIdx.x;                        \
    unsigned total = (unsigned)n * (unsigned)fout4;                            \
    if(idx >= total) return;                                                   \
    unsigned row = idx / fout4;                                                \
    unsigned cg  = idx - row*fout4;                                            \
    const float4* sWv = (const float4*)sW;                                     \
    float4 acc = {0.f,0.f,0.f,0.f};                                            \
    for(int k4 = 0; k4 < fin4; k4++){                                          \
        float4 hv = LOAD_HV;                                                   \
        int kb = k4*4;                                                         \
        float4 w;                                                              \
        w = sWv[(unsigned)(kb+0)*fout4 + cg];                                  \
        acc.x += hv.x*w.x; acc.y += hv.x*w.y; acc.z += hv.x*w.z; acc.w += hv.x*w.w; \
        w = sWv[(unsigned)(kb+1)*fout4 + cg];                                  \
        acc.x += hv.y*w.x; acc.y += hv.y*w.y; acc.z += hv.y*w.z; acc.w += hv.y*w.w; \
        w = sWv[(unsigned)(kb+2)*fout4 + cg];                                  \
        acc.x += hv.z*w.x; acc.y += hv.z*w.y; acc.z += hv.z*w.z; acc.w += hv.z*w.w; \
        w = sWv[(unsigned)(kb+3)*fout4 + cg];                                  \
        acc.x += hv.w*w.x; acc.y += hv.w*w.y; acc.z += hv.w*w.z; acc.w += hv.w*w.w; \
    }                                                                          \
    if(bias){                                                                  \
        const float4* bv = (const float4*)bias;                                \
        float4 b = bv[cg];                                                     \
        acc.x = fmaxf(acc.x + b.x, 0.f); acc.y = fmaxf(acc.y + b.y, 0.f);      \
        acc.z = fmaxf(acc.z + b.z, 0.f); acc.w = fmaxf(acc.w + b.w, 0.f);      \
    }                                                                          \
    if(dinv){                                                                  \
        float dd = dinv[row];                                                  \
        acc.x *= dd; acc.y *= dd; acc.z *= dd; acc.w *= dd;                    \
    }                                                                          \
    t[(size_t)row*out_sc + cg] = f4toh4(acc);

// fp32 input: fin_s4 = row stride in float4 units
__global__ void k_gemm_f32(const float* __restrict__ h, const float* __restrict__ W,
                           h4* __restrict__ t, int n, int fin4, int fin_s4,
                           int fout4, int out_sc,
                           const float* __restrict__ dinv, const float* __restrict__ bias){
    const float4* hr4 = (const float4*)h;
    GEMM_BODY(hr4[(size_t)row*fin_s4 + k4])
}

// fp16 input: fin_s4 = row stride in h4 units
__global__ void k_gemm_f16(const h4* __restrict__ h, const float* __restrict__ W,
                           h4* __restrict__ t, int n, int fin4, int fin_s4,
                           int fout4, int out_sc,
                           const float* __restrict__ dinv, const float* __restrict__ bias){
    GEMM_BODY(h4tof4(h[(size_t)row*fin_s4 + k4]))
}

// out[d] = f( dinv[d] * (t[d] + sum_{s->d} t[s]) ); 4-edge unroll for MLP
__global__ void k_gather(const int* __restrict__ cursor, const int* __restrict__ csr_src,
                         const h4* __restrict__ t, const float* __restrict__ dinv,
                         const float* __restrict__ bias, h4* __restrict__ out,
                         int n, int f4, int sc, int prescale_out){
    unsigned idx = blockIdx.x*blockDim.x + threadIdx.x;
    unsigned total = (unsigned)n * (unsigned)f4;
    if(idx >= total) return;
    unsigned d  = idx / f4;
    unsigned cg = idx - d*f4;
    int start = (d == 0) ? 0 : cursor[d-1];
    int end   = cursor[d];
    float4 a0 = h4tof4(t[(size_t)d*sc + cg]);    // self-loop contribution
    float4 a1 = {0,0,0,0}, a2 = {0,0,0,0}, a3 = {0,0,0,0};
    int j = start;
    for(; j + 4 <= end; j += 4){
        int s0 = csr_src[j], s1 = csr_src[j+1], s2 = csr_src[j+2], s3 = csr_src[j+3];
        float4 v0 = h4tof4(t[(size_t)s0*sc + cg]);   // 4 independent loads in flight
        float4 v1 = h4tof4(t[(size_t)s1*sc + cg]);
        float4 v2 = h4tof4(t[(size_t)s2*sc + cg]);
        float4 v3 = h4tof4(t[(size_t)s3*sc + cg]);
        a0.x += v0.x; a0.y += v0.y; a0.z += v0.z; a0.w += v0.w;
        a1.x += v1.x; a1.y += v1.y; a1.z += v1.z; a1.w += v1.w;
        a2.x += v2.x; a2.y += v2.y; a2.z += v2.z; a2.w += v2.w;
        a3.x += v3.x; a3.y += v3.y; a3.z += v3.z; a3.w += v3.w;
    }
    for(; j < end; j++){
        float4 v = h4tof4(t[(size_t)csr_src[j]*sc + cg]);
        a0.x += v.x; a0.y += v.y; a0.z += v.z; a0.w += v.w;
    }
    float4 acc;
    acc.x = (a0.x + a1.x) + (a2.x + a3.x);
    acc.y = (a0.y + a1.y) + (a2.y + a3.y);
    acc.z = (a0.z + a1.z) + (a2.z + a3.z);
    acc.w = (a0.w + a1.w) + (a2.w + a3.w);
    float dd = dinv[d];
    acc.x *= dd; acc.y *= dd; acc.z *= dd; acc.w *= dd;
    if(bias){
        const float4* bv = (const float4*)bias;
        float4 b = bv[cg];
        acc.x = fmaxf(acc.x + b.x, 0.f); acc.y = fmaxf(acc.y + b.y, 0.f);
        acc.z = fmaxf(acc.z + b.z, 0.f); acc.w = fmaxf(acc.w + b.w, 0.f);
    }
    if(prescale_out){
        acc.x *= dd; acc.y *= dd; acc.z *= dd; acc.w *= dd;
    }
    out[(size_t)d*sc + cg] = f4toh4(acc);
}

// one block (64 threads) per graph; batch sorted, segments non-empty. pooled fp32.
__global__ void k_pool_seg(const h4* __restrict__ h, const int* __restrict__ batch,
                           float* __restrict__ pooled, int n, int f4, int sc){
    int g = blockIdx.x;
    int lo = 0, hi = n;
    while(lo < hi){ int mid = (lo + hi) >> 1; if(batch[mid] < g) lo = mid + 1; else hi = mid; }
    int start = lo;
    hi = n;
    while(lo < hi){ int mid = (lo + hi) >> 1; if(batch[mid] < g + 1) lo = mid + 1; else hi = mid; }
    int end = lo;

    int t  = threadIdx.x;
    int rg = t >> 4;
    int cg = t & 15;
    float4 m = {0.f, 0.f, 0.f, 0.f};
    if(cg < f4){
        for(int r = start + rg; r < end; r += 4){
            float4 v = h4tof4(h[(size_t)r*sc + cg]);
            m.x = fmaxf(m.x, v.x); m.y = fmaxf(m.y, v.y);
            m.z = fmaxf(m.z, v.z); m.w = fmaxf(m.w, v.w);
        }
    }
    for(int off = 32; off >= 16; off >>= 1){
        m.x = fmaxf(m.x, __shfl_xor(m.x, off, 64));
        m.y = fmaxf(m.y, __shfl_xor(m.y, off, 64));
        m.z = fmaxf(m.z, __shfl_xor(m.z, off, 64));
        m.w = fmaxf(m.w, __shfl_xor(m.w, off, 64));
    }
    if(t < f4) ((float4*)pooled)[(size_t)g*f4 + t] = m;
}

// ---------- head: split-K GEMM ----------
__global__ void k_headmm(const float* __restrict__ feature, const float* __restrict__ Wf1,
                         float* __restrict__ partial, int G, int FEAT, int H){
    __shared__ float sfeat[128*GB];
    int g0 = blockIdx.x*GB;
    int ks = blockIdx.y;
    int Kc = (FEAT + KS - 1)/KS;
    int k0 = ks*Kc;
    int k1 = min(FEAT, k0 + Kc);
    int kc = k1 - k0;
    int t  = threadIdx.x;

    for(int idx = t; idx < GB*128; idx += 256){
        int gi = idx >> 7, kk = idx & 127;
        if(kk < kc) sfeat[kk*GB + gi] = feature[(size_t)(g0+gi)*FEAT + k0 + kk];
    }
    __syncthreads();

    int h  = t & 127;
    int gq = t >> 7;
    const float* wp = Wf1 + (size_t)k0*H + h;
    float4 a = {0.f,0.f,0.f,0.f};
    const float4* sf = (const float4*)(sfeat) + gq;
    for(int kk = 0; kk < kc; kk++){
        float w = wp[(size_t)kk*H];
        float4 f = sf[kk*2];
        a.x += f.x*w; a.y += f.y*w; a.z += f.z*w; a.w += f.w*w;
    }
    float* pp = partial + ((size_t)ks*G + g0 + gq*4)*H + h;
    pp[0] = a.x; pp[H] = a.y; pp[2*H] = a.z; pp[3*H] = a.w;
}

__global__ void k_headfin(const float* __restrict__ partial, const float* __restrict__ bf1,
                          const float* __restrict__ Wf2, const float* __restrict__ bf2,
                          const float* __restrict__ pooled, const float* __restrict__ Wg,
                          const float* __restrict__ bg, float* __restrict__ out,
                          int G, int H, int F){
    int g  = blockIdx.x*4 + (threadIdx.x >> 6);
    int h2 = threadIdx.x & 63;
    float2 s = {0.f, 0.f};
    for(int ks = 0; ks < KS; ks++){
        float2 p = ((const float2*)(partial + ((size_t)ks*G + g)*H))[h2];
        s.x += p.x; s.y += p.y;
    }
    float2 b  = ((const float2*)bf1)[h2];
    float2 w2 = ((const float2*)Wf2)[h2];
    float y = fmaxf(s.x + b.x, 0.f)*w2.x + fmaxf(s.y + b.y, 0.f)*w2.y;
    float v = (h2 < F) ? pooled[(size_t)g*F + h2]*Wg[h2] : 0.f;
    for(int off = 32; off; off >>= 1){
        y += __shfl_xor(y, off, 64);
        v += __shfl_xor(v, off, 64);
    }
    if(h2 == 0) out[g] = fmaxf(v + bg[0], 0.f) + y + bf2[0];
}

extern "C" void kernel_launch(void* const* d_in, const int* in_sizes, int n_in,
                              void* d_out, int out_size, void* d_ws, size_t ws_size,
                              hipStream_t stream) {
    const float* x       = (const float*)d_in[0];
    const int*   ei      = (const int*)  d_in[1];
    const int*   batch   = (const int*)  d_in[2];
    const float* feature = (const float*)d_in[3];
    const float* W1 = (const float*)d_in[4];  const float* b1 = (const float*)d_in[5];
    const float* W2 = (const float*)d_in[6];  const float* b2 = (const float*)d_in[7];
    const float* W3 = (const float*)d_in[8];  const float* b3 = (const float*)d_in[9];
    const float* Wg = (const float*)d_in[10]; const float* bg = (const float*)d_in[11];
    const float* Wf1= (const float*)d_in[12]; const float* bf1= (const float*)d_in[13];
    const float* Wf2= (const float*)d_in[14]; const float* bf2= (const float*)d_in[15];
    float* out = (float*)d_out;

    const int N    = in_sizes[2];          // 100000
    const int E    = in_sizes[1] / 2;      // 1000000
    const int G    = out_size;             // 1024
    const int F    = in_sizes[5];          // 44
    const int F2   = in_sizes[7];          // 88
    const int FEAT = in_sizes[3] / G;      // 1019
    const int H    = in_sizes[13];         // 128
    const int F4   = F  / 4;               // 11 chunks
    const int F24  = F2 / 4;               // 22 chunks
    const int SC   = 12;                   // F-row stride in h4 chunks (44 -> 48 halves, 96 B)
    const int SC2  = 22;                   // F2-row stride in h4 chunks (88 halves, packed)

    const int NB    = cdiv(N, 1 << BSH);   // 98 coarse buckets
    const int chunk = cdiv(E, NBLK1);
    const int M     = NB * NBLK1;

    // workspace layout (4B units)
    float* wsf    = (float*)d_ws;
    float* dinv   = wsf;                         // N floats
    int*   cursor = (int*)(dinv + N);            // N ints
    int*   csr    = cursor + N;                  // E ints
    h4*    bufA   = (h4*)(csr + E);              // N*SC h4
    h4*    bufB   = bufA + (size_t)N*SC;         // N*SC2 h4
    h4*    bufC   = bufB + (size_t)N*SC2;        // N*SC h4
    float* pooled = (float*)(bufC + (size_t)N*SC);  // G*F floats
    // time-shared aliases of bufB (dead outside conv2-out..conv3-in window):
    int2*  pairs  = (int2*)bufB;                 // E int2   (CSR build)
    int*   cnt_t  = (int*)bufB + 2*(size_t)E;    // M ints   (CSR build)
    float* partial= (float*)bufB;                // KS*G*H floats (head, after conv3 gemm)

    // ---- CSR build (counting sort; no global atomics) ----
    k_bcount  <<<NBLK1, TPB, 0, stream>>>(ei + E, cnt_t, E, NB, chunk);
    k_bscan   <<<1, 1024, 0, stream>>>(cnt_t, M);
    k_bscatter<<<NBLK1, TPB, 0, stream>>>(ei, cnt_t, pairs, E, NB, chunk);
    k_build   <<<NB, TPB, 0, stream>>>(pairs, cnt_t, csr, cursor, dinv, N, E, NB);

    // ---- conv1 (transform-first): bufA = dinv.*(x@W1) ; bufC = dinv.*relu(dinv*agg+b1) ----
    {
        unsigned tot = (unsigned)N*F4;
        k_gemm_f32<<<cdiv(tot,TPB), TPB, F*F*sizeof(float), stream>>>(
            x, W1, bufA, N, F/4, F/4, F4, SC, dinv, nullptr);
        k_gather<<<cdiv(tot,TPB), TPB, 0, stream>>>(cursor, csr, bufA, dinv, b1, bufC, N, F4, SC, 1);
    }
    // ---- conv2 (aggregate-first): bufA = dinv*agg(bufC) ; bufB = relu(bufA@W2+b2) ----
    {
        unsigned tot = (unsigned)N*F4;
        k_gather<<<cdiv(tot,TPB), TPB, 0, stream>>>(cursor, csr, bufC, dinv, nullptr, bufA, N, F4, SC, 0);
        unsigned tot2 = (unsigned)N*F24;
        k_gemm_f16<<<cdiv(tot2,TPB), TPB, F*F2*sizeof(float), stream>>>(
            bufA, W2, bufB, N, F/4, SC, F24, SC2, nullptr, b2);
    }
    // ---- conv3 (transform-first): bufA = dinv.*(bufB@W3) ; bufC = relu(dinv*agg+b3) ----
    {
        unsigned tot = (unsigned)N*F4;
        k_gemm_f16<<<cdiv(tot,TPB), TPB, F2*F*sizeof(float), stream>>>(
            bufB, W3, bufA, N, F2/4, SC2, F4, SC, dinv, nullptr);
        k_gather<<<cdiv(tot,TPB), TPB, 0, stream>>>(cursor, csr, bufA, dinv, b3, bufC, N, F4, SC, 0);
    }
    // ---- global max pool ----
    k_pool_seg<<<G, 64, 0, stream>>>(bufC, batch, pooled, N, F4, SC);

    // ---- head: split-K GEMM into partial (aliases bufB; conv3 gemm already consumed it) ----
    {
        dim3 grid(G/GB, KS);
        k_headmm<<<grid, 256, 0, stream>>>(feature, Wf1, partial, G, FEAT, H);
        k_headfin<<<G/4, 256, 0, stream>>>(partial, bf1, Wf2, bf2, pooled, Wg, bg, out, G, H, F);
    }
}

// Round 9
// 348.920 us; speedup vs baseline: 1.3579x; 1.0302x over previous
//
#include <hip/hip_runtime.h>
#include <hip/hip_fp16.h>

#define TPB 256
#define NBLK1 256          // pass-1 blocks
#define BSH 10             // bucket shift: 1024 nodes per bucket
#define MAXBE 12288        // max edges/bucket (mean 10240) -> 48KB LDS
#define KS 8               // head GEMM K-splits
#define GB 8               // head GEMM graphs per block
#define GROWS 4            // GEMM row-batching factor

static inline int cdiv(long long a, int b){ return (int)((a + b - 1)/b); }

// 4 halves = 8 bytes, 8-byte aligned so loads are single dwordx2
struct __align__(8) h4 { __half2 a, b; };
__device__ inline float4 h4tof4(h4 v){
    float2 lo = __half22float2(v.a), hi = __half22float2(v.b);
    return make_float4(lo.x, lo.y, hi.x, hi.y);
}
__device__ inline h4 f4toh4(float4 v){
    h4 r; r.a = __floats2half2_rn(v.x, v.y); r.b = __floats2half2_rn(v.z, v.w); return r;
}

// ---------- CSR build: two-level counting sort, no global atomics ----------

__global__ void k_bcount(const int* __restrict__ dst, int* __restrict__ cnt_t,
                         int E, int NB, int chunk){
    __shared__ int hist[256];
    int blk = blockIdx.x;
    for(int i = threadIdx.x; i < NB; i += blockDim.x) hist[i] = 0;
    __syncthreads();
    int lo = blk*chunk, hi = min(E, lo + chunk);
    for(int e = lo + threadIdx.x; e < hi; e += blockDim.x)
        atomicAdd(&hist[dst[e] >> BSH], 1);
    __syncthreads();
    for(int b = threadIdx.x; b < NB; b += blockDim.x)
        cnt_t[b*NBLK1 + blk] = hist[b];
}

__global__ void k_bscan(int* __restrict__ cnt_t, int M){
    __shared__ int part[1024];
    int t = threadIdx.x;
    int IT = (M + 1023) >> 10;
    int base = t*IT;
    int s = 0;
    for(int i = 0; i < IT; i++){ int k = base + i; if(k < M) s += cnt_t[k]; }
    part[t] = s;
    __syncthreads();
    for(int off = 1; off < 1024; off <<= 1){
        int u = (t >= off) ? part[t-off] : 0;
        __syncthreads();
        part[t] += u;
        __syncthreads();
    }
    int run = (t == 0) ? 0 : part[t-1];
    for(int i = 0; i < IT; i++){
        int k = base + i;
        if(k < M){ int v = cnt_t[k]; cnt_t[k] = run; run += v; }
    }
}

__global__ void k_bscatter(const int* __restrict__ ei, const int* __restrict__ cnt_t,
                           int2* __restrict__ pairs, int E, int NB, int chunk){
    __shared__ int cur[256];
    int blk = blockIdx.x;
    for(int b = threadIdx.x; b < NB; b += blockDim.x) cur[b] = cnt_t[b*NBLK1 + blk];
    __syncthreads();
    int lo = blk*chunk, hi = min(E, lo + chunk);
    for(int e = lo + threadIdx.x; e < hi; e += blockDim.x){
        int s = ei[e], d = ei[E + e];
        int pos = atomicAdd(&cur[d >> BSH], 1);    // LDS atomic
        pairs[pos] = make_int2(s, d);
    }
}

__global__ void k_build(const int2* __restrict__ pairs, const int* __restrict__ cnt_t,
                        int* __restrict__ csr, int* __restrict__ cursor,
                        float* __restrict__ dinv, int N, int E, int NB){
    __shared__ int c[1024];
    __shared__ int so[1024];
    __shared__ int part[256];
    __shared__ int csrl[MAXBE];
    int b    = blockIdx.x;
    int n0   = b << BSH;
    int nn   = min(1024, N - n0);
    int base = cnt_t[b*NBLK1];
    int end  = (b+1 < NB) ? cnt_t[(b+1)*NBLK1] : E;
    int cntE = end - base;
    int t = threadIdx.x;
    for(int i = t; i < 1024; i += 256) c[i] = 0;
    __syncthreads();
    for(int i = t; i < cntE; i += 256)
        atomicAdd(&c[pairs[base + i].y - n0], 1);   // LDS atomic
    __syncthreads();
    int i0 = t*4;
    int l0 = c[i0], l1 = c[i0+1], l2 = c[i0+2], l3 = c[i0+3];
    part[t] = l0 + l1 + l2 + l3;
    __syncthreads();
    for(int off = 1; off < 256; off <<= 1){
        int u = (t >= off) ? part[t-off] : 0;
        __syncthreads();
        part[t] += u;
        __syncthreads();
    }
    int run = (t == 0) ? 0 : part[t-1];
    so[i0] = run; so[i0+1] = run + l0; so[i0+2] = run + l0 + l1; so[i0+3] = run + l0 + l1 + l2;
    __syncthreads();
    for(int i = t; i < nn; i += 256){
        int cc = c[i];
        cursor[n0 + i] = base + so[i] + cc;        // inclusive end offset
        dinv[n0 + i]   = rsqrtf((float)(cc + 1));  // +1 = self-loop
    }
    for(int i = t; i < 1024; i += 256) c[i] = so[i];
    __syncthreads();
    for(int i = t; i < cntE; i += 256){
        int2 p = pairs[base + i];
        int pos = atomicAdd(&c[p.y - n0], 1);      // LDS atomic
        csrl[pos] = p.x;
    }
    __syncthreads();
    for(int i = t; i < cntE; i += 256) csr[base + i] = csrl[i];   // coalesced
}

// ---------- compute (fp16 at rest, fp32 accumulate) ----------

// grid-stride body: each block stages W once, then handles GROWS x blockDim rows of work
#define GEMM_BODY(LOAD_HV)                                                     \
    extern __shared__ float sW[];                                              \
    int fout = fout4*4;                                                        \
    int fin = fin4*4;                                                          \
    for(int i = threadIdx.x; i < fin*fout; i += blockDim.x) sW[i] = W[i];      \
    __syncthreads();                                                           \
    unsigned total  = (unsigned)n * (unsigned)fout4;                           \
    unsigned stride = gridDim.x * blockDim.x;                                  \
    const float4* sWv = (const float4*)sW;                                     \
    for(unsigned idx = blockIdx.x*blockDim.x + threadIdx.x; idx < total; idx += stride){ \
        unsigned row = idx / fout4;                                            \
        unsigned cg  = idx - row*fout4;                                        \
        float4 acc = {0.f,0.f,0.f,0.f};                                        \
        for(int k4 = 0; k4 < fin4; k4++){                                      \
            float4 hv = LOAD_HV;                                               \
            int kb = k4*4;                                                     \
            float4 w;                                                          \
            w = sWv[(unsigned)(kb+0)*fout4 + cg];                              \
            acc.x += hv.x*w.x; acc.y += hv.x*w.y; acc.z += hv.x*w.z; acc.w += hv.x*w.w; \
            w = sWv[(unsigned)(kb+1)*fout4 + cg];                              \
            acc.x += hv.y*w.x; acc.y += hv.y*w.y; acc.z += hv.y*w.z; acc.w += hv.y*w.w; \
            w = sWv[(unsigned)(kb+2)*fout4 + cg];                              \
            acc.x += hv.z*w.x; acc.y += hv.z*w.y; acc.z += hv.z*w.z; acc.w += hv.z*w.w; \
            w = sWv[(unsigned)(kb+3)*fout4 + cg];                              \
            acc.x += hv.w*w.x; acc.y += hv.w*w.y; acc.z += hv.w*w.z; acc.w += hv.w*w.w; \
        }                                                                      \
        if(bias){                                                              \
            const float4* bv = (const float4*)bias;                            \
            float4 b = bv[cg];                                                 \
            acc.x = fmaxf(acc.x + b.x, 0.f); acc.y = fmaxf(acc.y + b.y, 0.f);  \
            acc.z = fmaxf(acc.z + b.z, 0.f); acc.w = fmaxf(acc.w + b.w, 0.f);  \
        }                                                                      \
        if(dinv){                                                              \
            float dd = dinv[row];                                              \
            acc.x *= dd; acc.y *= dd; acc.z *= dd; acc.w *= dd;                \
        }                                                                      \
        t[(size_t)row*out_sc + cg] = f4toh4(acc);                              \
    }

// fp32 input: fin_s4 = row stride in float4 units
__global__ void k_gemm_f32(const float* __restrict__ h, const float* __restrict__ W,
                           h4* __restrict__ t, int n, int fin4, int fin_s4,
                           int fout4, int out_sc,
                           const float* __restrict__ dinv, const float* __restrict__ bias){
    const float4* hr4 = (const float4*)h;
    GEMM_BODY(hr4[(size_t)row*fin_s4 + k4])
}

// fp16 input: fin_s4 = row stride in h4 units
__global__ void k_gemm_f16(const h4* __restrict__ h, const float* __restrict__ W,
                           h4* __restrict__ t, int n, int fin4, int fin_s4,
                           int fout4, int out_sc,
                           const float* __restrict__ dinv, const float* __restrict__ bias){
    GEMM_BODY(h4tof4(h[(size_t)row*fin_s4 + k4]))
}

// out[d] = f( dinv[d] * (t[d] + sum_{s->d} t[s]) ); 8-edge unroll for MLP
__global__ void k_gather(const int* __restrict__ cursor, const int* __restrict__ csr_src,
                         const h4* __restrict__ t, const float* __restrict__ dinv,
                         const float* __restrict__ bias, h4* __restrict__ out,
                         int n, int f4, int sc, int prescale_out){
    unsigned idx = blockIdx.x*blockDim.x + threadIdx.x;
    unsigned total = (unsigned)n * (unsigned)f4;
    if(idx >= total) return;
    unsigned d  = idx / f4;
    unsigned cg = idx - d*f4;
    int start = (d == 0) ? 0 : cursor[d-1];
    int end   = cursor[d];
    float4 a0 = h4tof4(t[(size_t)d*sc + cg]);    // self-loop contribution
    float4 a1 = {0,0,0,0}, a2 = {0,0,0,0}, a3 = {0,0,0,0};
    int j = start;
    for(; j + 8 <= end; j += 8){
        int s0 = csr_src[j],   s1 = csr_src[j+1], s2 = csr_src[j+2], s3 = csr_src[j+3];
        int s4 = csr_src[j+4], s5 = csr_src[j+5], s6 = csr_src[j+6], s7 = csr_src[j+7];
        h4 r0 = t[(size_t)s0*sc + cg];   // 8 independent dwordx2 loads in flight
        h4 r1 = t[(size_t)s1*sc + cg];
        h4 r2 = t[(size_t)s2*sc + cg];
        h4 r3 = t[(size_t)s3*sc + cg];
        h4 r4 = t[(size_t)s4*sc + cg];
        h4 r5 = t[(size_t)s5*sc + cg];
        h4 r6 = t[(size_t)s6*sc + cg];
        h4 r7 = t[(size_t)s7*sc + cg];
        float4 v0 = h4tof4(r0), v1 = h4tof4(r1), v2 = h4tof4(r2), v3 = h4tof4(r3);
        float4 v4 = h4tof4(r4), v5 = h4tof4(r5), v6 = h4tof4(r6), v7 = h4tof4(r7);
        a0.x += v0.x + v4.x; a0.y += v0.y + v4.y; a0.z += v0.z + v4.z; a0.w += v0.w + v4.w;
        a1.x += v1.x + v5.x; a1.y += v1.y + v5.y; a1.z += v1.z + v5.z; a1.w += v1.w + v5.w;
        a2.x += v2.x + v6.x; a2.y += v2.y + v6.y; a2.z += v2.z + v6.z; a2.w += v2.w + v6.w;
        a3.x += v3.x + v7.x; a3.y += v3.y + v7.y; a3.z += v3.z + v7.z; a3.w += v3.w + v7.w;
    }
    for(; j + 4 <= end; j += 4){
        int s0 = csr_src[j], s1 = csr_src[j+1], s2 = csr_src[j+2], s3 = csr_src[j+3];
        float4 v0 = h4tof4(t[(size_t)s0*sc + cg]);
        float4 v1 = h4tof4(t[(size_t)s1*sc + cg]);
        float4 v2 = h4tof4(t[(size_t)s2*sc + cg]);
        float4 v3 = h4tof4(t[(size_t)s3*sc + cg]);
        a0.x += v0.x; a0.y += v0.y; a0.z += v0.z; a0.w += v0.w;
        a1.x += v1.x; a1.y += v1.y; a1.z += v1.z; a1.w += v1.w;
        a2.x += v2.x; a2.y += v2.y; a2.z += v2.z; a2.w += v2.w;
        a3.x += v3.x; a3.y += v3.y; a3.z += v3.z; a3.w += v3.w;
    }
    for(; j < end; j++){
        float4 v = h4tof4(t[(size_t)csr_src[j]*sc + cg]);
        a0.x += v.x; a0.y += v.y; a0.z += v.z; a0.w += v.w;
    }
    float4 acc;
    acc.x = (a0.x + a1.x) + (a2.x + a3.x);
    acc.y = (a0.y + a1.y) + (a2.y + a3.y);
    acc.z = (a0.z + a1.z) + (a2.z + a3.z);
    acc.w = (a0.w + a1.w) + (a2.w + a3.w);
    float dd = dinv[d];
    acc.x *= dd; acc.y *= dd; acc.z *= dd; acc.w *= dd;
    if(bias){
        const float4* bv = (const float4*)bias;
        float4 b = bv[cg];
        acc.x = fmaxf(acc.x + b.x, 0.f); acc.y = fmaxf(acc.y + b.y, 0.f);
        acc.z = fmaxf(acc.z + b.z, 0.f); acc.w = fmaxf(acc.w + b.w, 0.f);
    }
    if(prescale_out){
        acc.x *= dd; acc.y *= dd; acc.z *= dd; acc.w *= dd;
    }
    out[(size_t)d*sc + cg] = f4toh4(acc);
}

// ---------- head: split-K GEMM ----------
__global__ void k_headmm(const float* __restrict__ feature, const float* __restrict__ Wf1,
                         float* __restrict__ partial, int G, int FEAT, int H){
    __shared__ float sfeat[128*GB];
    int g0 = blockIdx.x*GB;
    int ks = blockIdx.y;
    int Kc = (FEAT + KS - 1)/KS;
    int k0 = ks*Kc;
    int k1 = min(FEAT, k0 + Kc);
    int kc = k1 - k0;
    int t  = threadIdx.x;

    for(int idx = t; idx < GB*128; idx += 256){
        int gi = idx >> 7, kk = idx & 127;
        if(kk < kc) sfeat[kk*GB + gi] = feature[(size_t)(g0+gi)*FEAT + k0 + kk];
    }
    __syncthreads();

    int h  = t & 127;
    int gq = t >> 7;
    const float* wp = Wf1 + (size_t)k0*H + h;
    float4 a = {0.f,0.f,0.f,0.f};
    const float4* sf = (const float4*)(sfeat) + gq;
    for(int kk = 0; kk < kc; kk++){
        float w = wp[(size_t)kk*H];
        float4 f = sf[kk*2];
        a.x += f.x*w; a.y += f.y*w; a.z += f.z*w; a.w += f.w*w;
    }
    float* pp = partial + ((size_t)ks*G + g0 + gq*4)*H + h;
    pp[0] = a.x; pp[H] = a.y; pp[2*H] = a.z; pp[3*H] = a.w;
}

// fused pool + epilogue: 4 graphs/block (one per wave), 256 threads.
// wave: pool graph g from hbuf (batch sorted, non-empty), then
// x2 = relu(C + bf1) @ Wf2 + bf2 ; x1 = relu(pooled.Wg + bg); out = x1 + x2.
// Requires H==128, f4 <= 16.
__global__ void k_headfin(const float* __restrict__ partial, const float* __restrict__ bf1,
                          const float* __restrict__ Wf2, const float* __restrict__ bf2,
                          const h4* __restrict__ hbuf, const int* __restrict__ batch,
                          const float* __restrict__ Wg, const float* __restrict__ bg,
                          float* __restrict__ out, int G, int H, int f4, int sc, int n){
    int g    = blockIdx.x*4 + (threadIdx.x >> 6);
    int lane = threadIdx.x & 63;

    // --- pool graph g (per-wave, no atomics) ---
    int lo = 0, hi = n;
    while(lo < hi){ int mid = (lo + hi) >> 1; if(batch[mid] < g) lo = mid + 1; else hi = mid; }
    int start = lo;
    hi = n;
    while(lo < hi){ int mid = (lo + hi) >> 1; if(batch[mid] < g + 1) lo = mid + 1; else hi = mid; }
    int end = lo;

    int rg = lane >> 4;          // row group 0..3
    int cg = lane & 15;          // chunk; active when < f4
    float4 m = {0.f, 0.f, 0.f, 0.f};
    if(cg < f4){
        for(int r = start + rg; r < end; r += 4){
            float4 v = h4tof4(hbuf[(size_t)r*sc + cg]);
            m.x = fmaxf(m.x, v.x); m.y = fmaxf(m.y, v.y);
            m.z = fmaxf(m.z, v.z); m.w = fmaxf(m.w, v.w);
        }
    }
    for(int off = 32; off >= 16; off >>= 1){
        m.x = fmaxf(m.x, __shfl_xor(m.x, off, 64));
        m.y = fmaxf(m.y, __shfl_xor(m.y, off, 64));
        m.z = fmaxf(m.z, __shfl_xor(m.z, off, 64));
        m.w = fmaxf(m.w, __shfl_xor(m.w, off, 64));
    }
    // x1 partial dot: only lanes 0..15 contribute (all lanes hold group max keyed by lane&15)
    float v = 0.f;
    if(lane < 16 && cg < f4)
        v = m.x*Wg[4*cg] + m.y*Wg[4*cg+1] + m.z*Wg[4*cg+2] + m.w*Wg[4*cg+3];

    // --- x2 part: combine split-K partials ---
    int h2 = lane;               // float2 over H=128
    float2 s = {0.f, 0.f};
    for(int ks = 0; ks < KS; ks++){
        float2 p = ((const float2*)(partial + ((size_t)ks*G + g)*H))[h2];
        s.x += p.x; s.y += p.y;
    }
    float2 b  = ((const float2*)bf1)[h2];
    float2 w2 = ((const float2*)Wf2)[h2];
    float y = fmaxf(s.x + b.x, 0.f)*w2.x + fmaxf(s.y + b.y, 0.f)*w2.y;

    for(int off = 32; off; off >>= 1){
        y += __shfl_xor(y, off, 64);
        v += __shfl_xor(v, off, 64);
    }
    if(lane == 0) out[g] = fmaxf(v + bg[0], 0.f) + y + bf2[0];
}

extern "C" void kernel_launch(void* const* d_in, const int* in_sizes, int n_in,
                              void* d_out, int out_size, void* d_ws, size_t ws_size,
                              hipStream_t stream) {
    const float* x       = (const float*)d_in[0];
    const int*   ei      = (const int*)  d_in[1];
    const int*   batch   = (const int*)  d_in[2];
    const float* feature = (const float*)d_in[3];
    const float* W1 = (const float*)d_in[4];  const float* b1 = (const float*)d_in[5];
    const float* W2 = (const float*)d_in[6];  const float* b2 = (const float*)d_in[7];
    const float* W3 = (const float*)d_in[8];  const float* b3 = (const float*)d_in[9];
    const float* Wg = (const float*)d_in[10]; const float* bg = (const float*)d_in[11];
    const float* Wf1= (const float*)d_in[12]; const float* bf1= (const float*)d_in[13];
    const float* Wf2= (const float*)d_in[14]; const float* bf2= (const float*)d_in[15];
    float* out = (float*)d_out;

    const int N    = in_sizes[2];          // 100000
    const int E    = in_sizes[1] / 2;      // 1000000
    const int G    = out_size;             // 1024
    const int F    = in_sizes[5];          // 44
    const int F2   = in_sizes[7];          // 88
    const int FEAT = in_sizes[3] / G;      // 1019
    const int H    = in_sizes[13];         // 128
    const int F4   = F  / 4;               // 11 chunks
    const int F24  = F2 / 4;               // 22 chunks
    const int SC   = 12;                   // F-row stride in h4 chunks (44 -> 48 halves, 96 B)
    const int SC2  = 22;                   // F2-row stride in h4 chunks (88 halves, packed)

    const int NB    = cdiv(N, 1 << BSH);   // 98 coarse buckets
    const int chunk = cdiv(E, NBLK1);
    const int M     = NB * NBLK1;

    // workspace layout (4B units)
    float* wsf    = (float*)d_ws;
    float* dinv   = wsf;                         // N floats
    int*   cursor = (int*)(dinv + N);            // N ints
    int*   csr    = cursor + N;                  // E ints
    h4*    bufA   = (h4*)(csr + E);              // N*SC h4
    h4*    bufB   = bufA + (size_t)N*SC;         // N*SC2 h4
    h4*    bufC   = bufB + (size_t)N*SC2;        // N*SC h4
    // time-shared aliases of bufB (dead outside conv2-out..conv3-in window):
    int2*  pairs  = (int2*)bufB;                 // E int2   (CSR build)
    int*   cnt_t  = (int*)bufB + 2*(size_t)E;    // M ints   (CSR build)
    float* partial= (float*)bufB;                // KS*G*H floats (head, after conv3 gemm)

    // ---- CSR build (counting sort; no global atomics) ----
    k_bcount  <<<NBLK1, TPB, 0, stream>>>(ei + E, cnt_t, E, NB, chunk);
    k_bscan   <<<1, 1024, 0, stream>>>(cnt_t, M);
    k_bscatter<<<NBLK1, TPB, 0, stream>>>(ei, cnt_t, pairs, E, NB, chunk);
    k_build   <<<NB, TPB, 0, stream>>>(pairs, cnt_t, csr, cursor, dinv, N, E, NB);

    // ---- conv1 (transform-first): bufA = dinv.*(x@W1) ; bufC = dinv.*relu(dinv*agg+b1) ----
    {
        unsigned tot = (unsigned)N*F4;
        k_gemm_f32<<<cdiv(tot,TPB*GROWS), TPB, F*F*sizeof(float), stream>>>(
            x, W1, bufA, N, F/4, F/4, F4, SC, dinv, nullptr);
        k_gather<<<cdiv(tot,TPB), TPB, 0, stream>>>(cursor, csr, bufA, dinv, b1, bufC, N, F4, SC, 1);
    }
    // ---- conv2 (aggregate-first): bufA = dinv*agg(bufC) ; bufB = relu(bufA@W2+b2) ----
    {
        unsigned tot = (unsigned)N*F4;
        k_gather<<<cdiv(tot,TPB), TPB, 0, stream>>>(cursor, csr, bufC, dinv, nullptr, bufA, N, F4, SC, 0);
        unsigned tot2 = (unsigned)N*F24;
        k_gemm_f16<<<cdiv(tot2,TPB*GROWS), TPB, F*F2*sizeof(float), stream>>>(
            bufA, W2, bufB, N, F/4, SC, F24, SC2, nullptr, b2);
    }
    // ---- conv3 (transform-first): bufA = dinv.*(bufB@W3) ; bufC = relu(dinv*agg+b3) ----
    {
        unsigned tot = (unsigned)N*F4;
        k_gemm_f16<<<cdiv(tot,TPB*GROWS), TPB, F2*F*sizeof(float), stream>>>(
            bufB, W3, bufA, N, F2/4, SC2, F4, SC, dinv, nullptr);
        k_gather<<<cdiv(tot,TPB), TPB, 0, stream>>>(cursor, csr, bufA, dinv, b3, bufC, N, F4, SC, 0);
    }
    // ---- head: split-K GEMM into partial (aliases bufB; conv3 gemm already consumed it),
    //      then fused pool + epilogue ----
    {
        dim3 grid(G/GB, KS);
        k_headmm<<<grid, 256, 0, stream>>>(feature, Wf1, partial, G, FEAT, H);
        k_headfin<<<G/4, 256, 0, stream>>>(partial, bf1, Wf2, bf2, bufC, batch,
                                           Wg, bg, out, G, H, F4, SC, N);
    }
}

// Round 10
// 337.726 us; speedup vs baseline: 1.4029x; 1.0331x over previous
//
#include <hip/hip_runtime.h>
#include <hip/hip_fp16.h>

#define TPB 256
#define NBLK1 256          // CSR pass-1 blocks
#define BSH 10             // bucket shift: 1024 nodes per bucket
#define MAXBE 12288        // max edges/bucket -> 48KB LDS
#define KS 8               // head GEMM K-splits
#define GB 8               // head GEMM graphs per block
#define GROWS 4            // conv1 GEMM row-batching
#define NPB 42             // fused kernel nodes/block (42*6 = 252 <= 256)

static inline int cdiv(long long a, int b){ return (int)((a + b - 1)/b); }

// 8 halves = 16 bytes, 16-byte aligned -> single dwordx4 loads
struct __align__(16) h8 { __half2 a, b, c, d; };
struct float8 { float4 lo, hi; };
__device__ inline float8 h8tof8(h8 v){
    float2 t0 = __half22float2(v.a), t1 = __half22float2(v.b);
    float2 t2 = __half22float2(v.c), t3 = __half22float2(v.d);
    float8 r;
    r.lo = make_float4(t0.x, t0.y, t1.x, t1.y);
    r.hi = make_float4(t2.x, t2.y, t3.x, t3.y);
    return r;
}
__device__ inline h8 f8toh8(float8 v){
    h8 r;
    r.a = __floats2half2_rn(v.lo.x, v.lo.y); r.b = __floats2half2_rn(v.lo.z, v.lo.w);
    r.c = __floats2half2_rn(v.hi.x, v.hi.y); r.d = __floats2half2_rn(v.hi.z, v.hi.w);
    return r;
}
__device__ inline void f8acc(float8& a, float8 v){
    a.lo.x += v.lo.x; a.lo.y += v.lo.y; a.lo.z += v.lo.z; a.lo.w += v.lo.w;
    a.hi.x += v.hi.x; a.hi.y += v.hi.y; a.hi.z += v.hi.z; a.hi.w += v.hi.w;
}

// ---------- CSR build: two-level counting sort, no global atomics ----------

__global__ void k_bcount(const int* __restrict__ dst, int* __restrict__ cnt_t,
                         int E, int NB, int chunk){
    __shared__ int hist[256];
    int blk = blockIdx.x;
    for(int i = threadIdx.x; i < NB; i += blockDim.x) hist[i] = 0;
    __syncthreads();
    int lo = blk*chunk, hi = min(E, lo + chunk);
    for(int e = lo + threadIdx.x; e < hi; e += blockDim.x)
        atomicAdd(&hist[dst[e] >> BSH], 1);
    __syncthreads();
    for(int b = threadIdx.x; b < NB; b += blockDim.x)
        cnt_t[b*NBLK1 + blk] = hist[b];
}

__global__ void k_bscan(int* __restrict__ cnt_t, int M){
    __shared__ int part[1024];
    int t = threadIdx.x;
    int IT = (M + 1023) >> 10;
    int base = t*IT;
    int s = 0;
    for(int i = 0; i < IT; i++){ int k = base + i; if(k < M) s += cnt_t[k]; }
    part[t] = s;
    __syncthreads();
    for(int off = 1; off < 1024; off <<= 1){
        int u = (t >= off) ? part[t-off] : 0;
        __syncthreads();
        part[t] += u;
        __syncthreads();
    }
    int run = (t == 0) ? 0 : part[t-1];
    for(int i = 0; i < IT; i++){
        int k = base + i;
        if(k < M){ int v = cnt_t[k]; cnt_t[k] = run; run += v; }
    }
}

__global__ void k_bscatter(const int* __restrict__ ei, const int* __restrict__ cnt_t,
                           int2* __restrict__ pairs, int E, int NB, int chunk){
    __shared__ int cur[256];
    int blk = blockIdx.x;
    for(int b = threadIdx.x; b < NB; b += blockDim.x) cur[b] = cnt_t[b*NBLK1 + blk];
    __syncthreads();
    int lo = blk*chunk, hi = min(E, lo + chunk);
    for(int e = lo + threadIdx.x; e < hi; e += blockDim.x){
        int s = ei[e], d = ei[E + e];
        int pos = atomicAdd(&cur[d >> BSH], 1);    // LDS atomic
        pairs[pos] = make_int2(s, d);
    }
}

__global__ void k_build(const int2* __restrict__ pairs, const int* __restrict__ cnt_t,
                        int* __restrict__ csr, int* __restrict__ cursor,
                        float* __restrict__ dinv, int N, int E, int NB){
    __shared__ int c[1024];
    __shared__ int so[1024];
    __shared__ int part[256];
    __shared__ int csrl[MAXBE];
    int b    = blockIdx.x;
    int n0   = b << BSH;
    int nn   = min(1024, N - n0);
    int base = cnt_t[b*NBLK1];
    int end  = (b+1 < NB) ? cnt_t[(b+1)*NBLK1] : E;
    int cntE = end - base;
    int t = threadIdx.x;
    for(int i = t; i < 1024; i += 256) c[i] = 0;
    __syncthreads();
    for(int i = t; i < cntE; i += 256)
        atomicAdd(&c[pairs[base + i].y - n0], 1);   // LDS atomic
    __syncthreads();
    int i0 = t*4;
    int l0 = c[i0], l1 = c[i0+1], l2 = c[i0+2], l3 = c[i0+3];
    part[t] = l0 + l1 + l2 + l3;
    __syncthreads();
    for(int off = 1; off < 256; off <<= 1){
        int u = (t >= off) ? part[t-off] : 0;
        __syncthreads();
        part[t] += u;
        __syncthreads();
    }
    int run = (t == 0) ? 0 : part[t-1];
    so[i0] = run; so[i0+1] = run + l0; so[i0+2] = run + l0 + l1; so[i0+3] = run + l0 + l1 + l2;
    __syncthreads();
    for(int i = t; i < nn; i += 256){
        int cc = c[i];
        cursor[n0 + i] = base + so[i] + cc;        // inclusive end offset
        dinv[n0 + i]   = rsqrtf((float)(cc + 1));  // +1 = self-loop
    }
    for(int i = t; i < 1024; i += 256) c[i] = so[i];
    __syncthreads();
    for(int i = t; i < cntE; i += 256){
        int2 p = pairs[base + i];
        int pos = atomicAdd(&c[p.y - n0], 1);      // LDS atomic
        csrl[pos] = p.x;
    }
    __syncthreads();
    for(int i = t; i < cntE; i += 256) csr[base + i] = csrl[i];   // coalesced
}

// ---------- shared gather core: self + neighbor sum of one 16B chunk ----------
__device__ inline float8 gather_row(const int* __restrict__ cursor,
                                    const int* __restrict__ csr,
                                    const h8* __restrict__ t, int d, int cg){
    int start = (d == 0) ? 0 : cursor[d-1];
    int end   = cursor[d];
    float8 a0 = h8tof8(t[(size_t)d*6 + cg]);     // self-loop
    float8 a1 = {{0,0,0,0},{0,0,0,0}}, a2 = a1, a3 = a1;
    int j = start;
    for(; j + 8 <= end; j += 8){
        int s0 = csr[j],   s1 = csr[j+1], s2 = csr[j+2], s3 = csr[j+3];
        int s4 = csr[j+4], s5 = csr[j+5], s6 = csr[j+6], s7 = csr[j+7];
        h8 r0 = t[(size_t)s0*6 + cg];            // 8 independent dwordx4 in flight
        h8 r1 = t[(size_t)s1*6 + cg];
        h8 r2 = t[(size_t)s2*6 + cg];
        h8 r3 = t[(size_t)s3*6 + cg];
        h8 r4 = t[(size_t)s4*6 + cg];
        h8 r5 = t[(size_t)s5*6 + cg];
        h8 r6 = t[(size_t)s6*6 + cg];
        h8 r7 = t[(size_t)s7*6 + cg];
        f8acc(a0, h8tof8(r0)); f8acc(a1, h8tof8(r1));
        f8acc(a2, h8tof8(r2)); f8acc(a3, h8tof8(r3));
        f8acc(a0, h8tof8(r4)); f8acc(a1, h8tof8(r5));
        f8acc(a2, h8tof8(r6)); f8acc(a3, h8tof8(r7));
    }
    for(; j + 4 <= end; j += 4){
        int s0 = csr[j], s1 = csr[j+1], s2 = csr[j+2], s3 = csr[j+3];
        h8 r0 = t[(size_t)s0*6 + cg];
        h8 r1 = t[(size_t)s1*6 + cg];
        h8 r2 = t[(size_t)s2*6 + cg];
        h8 r3 = t[(size_t)s3*6 + cg];
        f8acc(a0, h8tof8(r0)); f8acc(a1, h8tof8(r1));
        f8acc(a2, h8tof8(r2)); f8acc(a3, h8tof8(r3));
    }
    for(; j < end; j++) f8acc(a0, h8tof8(t[(size_t)csr[j]*6 + cg]));
    f8acc(a0, a1); f8acc(a2, a3); f8acc(a0, a2);
    return a0;
}

// ---------- conv1 GEMM: t = dinv .* (x @ W1), fp32 in, h8 out ----------
__global__ void k_gemm1(const float* __restrict__ x, const float* __restrict__ W,
                        h8* __restrict__ t, int n, const float* __restrict__ dinv){
    __shared__ float sW[44*48];                   // [k][48], zero-padded cols
    for(int i = threadIdx.x; i < 44*48; i += blockDim.x){
        int k = i/48, j = i - k*48;
        sW[i] = (j < 44) ? W[k*44 + j] : 0.f;
    }
    __syncthreads();
    unsigned total  = (unsigned)n * 6u;
    unsigned stride = gridDim.x * blockDim.x;
    const float4* sWv = (const float4*)sW;        // 12 float4 per k
    for(unsigned idx = blockIdx.x*blockDim.x + threadIdx.x; idx < total; idx += stride){
        unsigned row = idx / 6u;
        unsigned cg  = idx - row*6u;
        const float4* xr = (const float4*)(x + (size_t)row*44);
        float8 acc = {{0,0,0,0},{0,0,0,0}};
        for(int k4 = 0; k4 < 11; k4++){
            float4 hv = xr[k4];
            int kb = k4*4;
            #pragma unroll
            for(int i = 0; i < 4; i++){
                float h = (i==0)?hv.x:(i==1)?hv.y:(i==2)?hv.z:hv.w;
                float4 wlo = sWv[(unsigned)(kb+i)*12 + cg*2];
                float4 whi = sWv[(unsigned)(kb+i)*12 + cg*2 + 1];
                acc.lo.x += h*wlo.x; acc.lo.y += h*wlo.y; acc.lo.z += h*wlo.z; acc.lo.w += h*wlo.w;
                acc.hi.x += h*whi.x; acc.hi.y += h*whi.y; acc.hi.z += h*whi.z; acc.hi.w += h*whi.w;
            }
        }
        float dd = dinv[row];
        acc.lo.x *= dd; acc.lo.y *= dd; acc.lo.z *= dd; acc.lo.w *= dd;
        acc.hi.x *= dd; acc.hi.y *= dd; acc.hi.z *= dd; acc.hi.w *= dd;
        t[(size_t)row*6 + cg] = f8toh8(acc);
    }
}

// ---------- plain gather: out = [prescale] relu(dinv*agg + bias) ----------
__global__ void k_gather8(const int* __restrict__ cursor, const int* __restrict__ csr,
                          const h8* __restrict__ t, const float* __restrict__ dinv,
                          const float* __restrict__ bias, h8* __restrict__ out,
                          int n, int prescale_out){
    __shared__ float sb[48];
    if(threadIdx.x < 48) sb[threadIdx.x] = (threadIdx.x < 44) ? bias[threadIdx.x] : 0.f;
    __syncthreads();
    unsigned idx = blockIdx.x*blockDim.x + threadIdx.x;
    unsigned total = (unsigned)n * 6u;
    if(idx >= total) return;
    unsigned d  = idx / 6u;
    unsigned cg = idx - d*6u;
    float8 acc = gather_row(cursor, csr, t, (int)d, (int)cg);
    float dd = dinv[d];
    const float4* sb4 = (const float4*)sb;
    float4 blo = sb4[cg*2], bhi = sb4[cg*2+1];
    acc.lo.x = fmaxf(acc.lo.x*dd + blo.x, 0.f); acc.lo.y = fmaxf(acc.lo.y*dd + blo.y, 0.f);
    acc.lo.z = fmaxf(acc.lo.z*dd + blo.z, 0.f); acc.lo.w = fmaxf(acc.lo.w*dd + blo.w, 0.f);
    acc.hi.x = fmaxf(acc.hi.x*dd + bhi.x, 0.f); acc.hi.y = fmaxf(acc.hi.y*dd + bhi.y, 0.f);
    acc.hi.z = fmaxf(acc.hi.z*dd + bhi.z, 0.f); acc.hi.w = fmaxf(acc.hi.w*dd + bhi.w, 0.f);
    if(prescale_out){
        acc.lo.x *= dd; acc.lo.y *= dd; acc.lo.z *= dd; acc.lo.w *= dd;
        acc.hi.x *= dd; acc.hi.y *= dd; acc.hi.z *= dd; acc.hi.w *= dd;
    }
    out[(size_t)d*6 + cg] = f8toh8(acc);
}

// ---------- fused conv2 + conv3-transform ----------
// in:  tin = h1' (prescaled). per node: t2 = dinv*(self+agg); h2 = relu(t2@W2+b2);
// out: tout = dinv*(h2@W3)   (the N x 88 intermediate never touches global memory)
__global__ void k_gconv2(const int* __restrict__ cursor, const int* __restrict__ csr,
                         const h8* __restrict__ tin, const float* __restrict__ dinv,
                         const float* __restrict__ W2, const float* __restrict__ b2,
                         const float* __restrict__ W3, h8* __restrict__ tout, int N){
    __shared__ float sW[44*88];     // W2 [k<44][88]; later reused for W3 [k<88][44]
    __shared__ float sb2[88];
    __shared__ float sAgg[NPB*48];
    __shared__ float sH2[NPB*88];
    __shared__ float sDinv[NPB];
    int t  = threadIdx.x;
    int d0 = blockIdx.x*NPB;
    int nn = min(NPB, N - d0);

    for(int i = t; i < 44*88; i += 256) sW[i] = W2[i];
    if(t < 88) sb2[t] = b2[t];
    __syncthreads();

    // phase 1: gather (6 threads per node)
    int ln = t/6, c = t - ln*6;
    if(t < NPB*6 && ln < nn){
        int d = d0 + ln;
        float8 acc = gather_row(cursor, csr, tin, d, c);
        float dd = dinv[d];
        if(c == 0) sDinv[ln] = dd;
        float* ar = sAgg + ln*48 + c*8;
        ar[0] = acc.lo.x*dd; ar[1] = acc.lo.y*dd; ar[2] = acc.lo.z*dd; ar[3] = acc.lo.w*dd;
        ar[4] = acc.hi.x*dd; ar[5] = acc.hi.y*dd; ar[6] = acc.hi.z*dd; ar[7] = acc.hi.w*dd;
    }
    __syncthreads();

    // phase 2: h2 = relu(t2 @ W2 + b2), float4-col chunks (22 per node)
    {
        const float4* sW4  = (const float4*)sW;    // 22 float4 per k
        const float4* sb24 = (const float4*)sb2;
        for(int o = t; o < nn*22; o += 256){
            int n_ = o/22, c4 = o - n_*22;
            const float* ar = sAgg + n_*48;
            float4 s = sb24[c4];
            for(int k = 0; k < 44; k++){
                float a = ar[k];
                float4 w = sW4[(unsigned)k*22 + c4];
                s.x += a*w.x; s.y += a*w.y; s.z += a*w.z; s.w += a*w.w;
            }
            float4* hp = (float4*)(sH2 + n_*88) + c4;
            hp[0] = make_float4(fmaxf(s.x,0.f), fmaxf(s.y,0.f), fmaxf(s.z,0.f), fmaxf(s.w,0.f));
        }
    }
    __syncthreads();

    // restage W3 (88 x 44)
    for(int i = t; i < 88*44; i += 256) sW[i] = W3[i];
    __syncthreads();

    // phase 3: t3 = dinv * (h2 @ W3); one h8 chunk per thread
    {
        const float4* sW4 = (const float4*)sW;     // 11 float4 per k (88 rows x 44 cols)
        for(int o = t; o < nn*6; o += 256){
            int n_ = o/6, cc = o - n_*6;
            const float* hr = sH2 + n_*88;
            float dd = sDinv[n_];
            float4 slo = {0,0,0,0}, shi = {0,0,0,0};
            if(cc < 5){
                for(int k = 0; k < 88; k++){
                    float h = hr[k];
                    float4 wlo = sW4[(unsigned)k*11 + cc*2];
                    float4 whi = sW4[(unsigned)k*11 + cc*2 + 1];
                    slo.x += h*wlo.x; slo.y += h*wlo.y; slo.z += h*wlo.z; slo.w += h*wlo.w;
                    shi.x += h*whi.x; shi.y += h*whi.y; shi.z += h*whi.z; shi.w += h*whi.w;
                }
            } else {                                // cols 40..43 valid, 44..47 pad=0
                for(int k = 0; k < 88; k++){
                    float h = hr[k];
                    float4 wlo = sW4[(unsigned)k*11 + 10];
                    slo.x += h*wlo.x; slo.y += h*wlo.y; slo.z += h*wlo.z; slo.w += h*wlo.w;
                }
            }
            float8 acc;
            acc.lo = make_float4(slo.x*dd, slo.y*dd, slo.z*dd, slo.w*dd);
            acc.hi = make_float4(shi.x*dd, shi.y*dd, shi.z*dd, shi.w*dd);
            tout[(size_t)(d0+n_)*6 + cc] = f8toh8(acc);
        }
    }
}

// ---------- head: split-K GEMM ----------
__global__ void k_headmm(const float* __restrict__ feature, const float* __restrict__ Wf1,
                         float* __restrict__ partial, int G, int FEAT, int H){
    __shared__ float sfeat[128*GB];
    int g0 = blockIdx.x*GB;
    int ks = blockIdx.y;
    int Kc = (FEAT + KS - 1)/KS;
    int k0 = ks*Kc;
    int k1 = min(FEAT, k0 + Kc);
    int kc = k1 - k0;
    int t  = threadIdx.x;

    for(int idx = t; idx < GB*128; idx += 256){
        int gi = idx >> 7, kk = idx & 127;
        if(kk < kc) sfeat[kk*GB + gi] = feature[(size_t)(g0+gi)*FEAT + k0 + kk];
    }
    __syncthreads();

    int h  = t & 127;
    int gq = t >> 7;
    const float* wp = Wf1 + (size_t)k0*H + h;
    float4 a = {0.f,0.f,0.f,0.f};
    const float4* sf = (const float4*)(sfeat) + gq;
    for(int kk = 0; kk < kc; kk++){
        float w = wp[(size_t)kk*H];
        float4 f = sf[kk*2];
        a.x += f.x*w; a.y += f.y*w; a.z += f.z*w; a.w += f.w*w;
    }
    float* pp = partial + ((size_t)ks*G + g0 + gq*4)*H + h;
    pp[0] = a.x; pp[H] = a.y; pp[2*H] = a.z; pp[3*H] = a.w;
}

// fused pool + epilogue: 4 graphs/block (one wave each).
__global__ void k_headfin(const float* __restrict__ partial, const float* __restrict__ bf1,
                          const float* __restrict__ Wf2, const float* __restrict__ bf2,
                          const h8* __restrict__ hbuf, const int* __restrict__ batch,
                          const float* __restrict__ Wg, const float* __restrict__ bg,
                          float* __restrict__ out, int G, int H, int n){
    int g    = blockIdx.x*4 + (threadIdx.x >> 6);
    int lane = threadIdx.x & 63;

    // segment bounds (batch sorted, non-empty)
    int lo = 0, hi = n;
    while(lo < hi){ int mid = (lo + hi) >> 1; if(batch[mid] < g) lo = mid + 1; else hi = mid; }
    int start = lo;
    hi = n;
    while(lo < hi){ int mid = (lo + hi) >> 1; if(batch[mid] < g + 1) lo = mid + 1; else hi = mid; }
    int end = lo;

    int rg = lane >> 3;          // 0..7 row groups
    int cg = lane & 7;           // 0..7 chunk slots, active < 6
    float8 m = {{0,0,0,0},{0,0,0,0}};    // valid floor: post-ReLU inputs
    if(cg < 6){
        for(int r = start + rg; r < end; r += 8){
            float8 v = h8tof8(hbuf[(size_t)r*6 + cg]);
            m.lo.x = fmaxf(m.lo.x, v.lo.x); m.lo.y = fmaxf(m.lo.y, v.lo.y);
            m.lo.z = fmaxf(m.lo.z, v.lo.z); m.lo.w = fmaxf(m.lo.w, v.lo.w);
            m.hi.x = fmaxf(m.hi.x, v.hi.x); m.hi.y = fmaxf(m.hi.y, v.hi.y);
            m.hi.z = fmaxf(m.hi.z, v.hi.z); m.hi.w = fmaxf(m.hi.w, v.hi.w);
        }
    }
    for(int off = 8; off <= 32; off <<= 1){
        m.lo.x = fmaxf(m.lo.x, __shfl_xor(m.lo.x, off, 64));
        m.lo.y = fmaxf(m.lo.y, __shfl_xor(m.lo.y, off, 64));
        m.lo.z = fmaxf(m.lo.z, __shfl_xor(m.lo.z, off, 64));
        m.lo.w = fmaxf(m.lo.w, __shfl_xor(m.lo.w, off, 64));
        m.hi.x = fmaxf(m.hi.x, __shfl_xor(m.hi.x, off, 64));
        m.hi.y = fmaxf(m.hi.y, __shfl_xor(m.hi.y, off, 64));
        m.hi.z = fmaxf(m.hi.z, __shfl_xor(m.hi.z, off, 64));
        m.hi.w = fmaxf(m.hi.w, __shfl_xor(m.hi.w, off, 64));
    }
    // x1 partial dot (only rg==0 lanes contribute; cols 44..47 are pad)
    float v = 0.f;
    if(rg == 0 && cg < 6){
        int base = cg*8;
        v = m.lo.x*Wg[base] + m.lo.y*Wg[base+1] + m.lo.z*Wg[base+2] + m.lo.w*Wg[base+3];
        if(cg < 5)
            v += m.hi.x*Wg[base+4] + m.hi.y*Wg[base+5] + m.hi.z*Wg[base+6] + m.hi.w*Wg[base+7];
    }

    // x2: combine split-K partials
    int h2 = lane;
    float2 s = {0.f, 0.f};
    for(int ks = 0; ks < KS; ks++){
        float2 p = ((const float2*)(partial + ((size_t)ks*G + g)*H))[h2];
        s.x += p.x; s.y += p.y;
    }
    float2 b  = ((const float2*)bf1)[h2];
    float2 w2 = ((const float2*)Wf2)[h2];
    float y = fmaxf(s.x + b.x, 0.f)*w2.x + fmaxf(s.y + b.y, 0.f)*w2.y;

    for(int off = 32; off; off >>= 1){
        y += __shfl_xor(y, off, 64);
        v += __shfl_xor(v, off, 64);
    }
    if(lane == 0) out[g] = fmaxf(v + bg[0], 0.f) + y + bf2[0];
}

extern "C" void kernel_launch(void* const* d_in, const int* in_sizes, int n_in,
                              void* d_out, int out_size, void* d_ws, size_t ws_size,
                              hipStream_t stream) {
    const float* x       = (const float*)d_in[0];
    const int*   ei      = (const int*)  d_in[1];
    const int*   batch   = (const int*)  d_in[2];
    const float* feature = (const float*)d_in[3];
    const float* W1 = (const float*)d_in[4];  const float* b1 = (const float*)d_in[5];
    const float* W2 = (const float*)d_in[6];  const float* b2 = (const float*)d_in[7];
    const float* W3 = (const float*)d_in[8];  const float* b3 = (const float*)d_in[9];
    const float* Wg = (const float*)d_in[10]; const float* bg = (const float*)d_in[11];
    const float* Wf1= (const float*)d_in[12]; const float* bf1= (const float*)d_in[13];
    const float* Wf2= (const float*)d_in[14]; const float* bf2= (const float*)d_in[15];
    float* out = (float*)d_out;

    const int N    = in_sizes[2];          // 100000
    const int E    = in_sizes[1] / 2;      // 1000000
    const int G    = out_size;             // 1024
    const int FEAT = in_sizes[3] / G;      // 1019
    const int H    = in_sizes[13];         // 128

    const int NB    = cdiv(N, 1 << BSH);   // 98 coarse buckets
    const int chunk = cdiv(E, NBLK1);
    const int M     = NB * NBLK1;

    // workspace layout (4B units)
    float* wsf    = (float*)d_ws;
    float* dinv   = wsf;                         // N floats
    int*   cursor = (int*)(dinv + N);            // N ints
    int*   csr    = cursor + N;                  // E ints
    h8*    bufA   = (h8*)(csr + E);              // N*6 h8 (t buffers)
    h8*    bufC   = bufA + (size_t)N*6;          // N*6 h8 (h buffers)
    float* scratch= (float*)(bufC + (size_t)N*6);
    int2*  pairs  = (int2*)scratch;              // E int2   (CSR build)
    int*   cnt_t  = (int*)(pairs + E);           // M ints   (CSR build)
    float* partial= scratch;                     // KS*G*H floats (head; pairs dead by then)

    // ---- CSR build (counting sort; no global atomics) ----
    k_bcount  <<<NBLK1, TPB, 0, stream>>>(ei + E, cnt_t, E, NB, chunk);
    k_bscan   <<<1, 1024, 0, stream>>>(cnt_t, M);
    k_bscatter<<<NBLK1, TPB, 0, stream>>>(ei, cnt_t, pairs, E, NB, chunk);
    k_build   <<<NB, TPB, 0, stream>>>(pairs, cnt_t, csr, cursor, dinv, N, E, NB);

    // ---- conv1: bufA = dinv.*(x@W1) ; bufC = dinv.*relu(dinv*agg + b1) ----
    k_gemm1  <<<cdiv((long long)N*6, TPB*GROWS), TPB, 0, stream>>>(x, W1, bufA, N, dinv);
    k_gather8<<<cdiv((long long)N*6, TPB), TPB, 0, stream>>>(cursor, csr, bufA, dinv, b1, bufC, N, 1);

    // ---- conv2 + conv3-transform fused: bufA = dinv.*(relu(dinv*agg(bufC)@W2+b2)@W3) ----
    k_gconv2 <<<cdiv(N, NPB), TPB, 0, stream>>>(cursor, csr, bufC, dinv, W2, b2, W3, bufA, N);

    // ---- conv3 aggregate: bufC = relu(dinv*agg(bufA) + b3) ----
    k_gather8<<<cdiv((long long)N*6, TPB), TPB, 0, stream>>>(cursor, csr, bufA, dinv, b3, bufC, N, 0);

    // ---- head: split-K GEMM + fused pool/epilogue ----
    {
        dim3 grid(G/GB, KS);
        k_headmm <<<grid, 256, 0, stream>>>(feature, Wf1, partial, G, FEAT, H);
        k_headfin<<<G/4, 256, 0, stream>>>(partial, bf1, Wf2, bf2, bufC, batch,
                                           Wg, bg, out, G, H, N);
    }
}